// Round 10
// baseline (333.013 us; speedup 1.0000x reference)
//
#include <hip/hip_runtime.h>
#include <hip/hip_bf16.h>

#define N_NODES 50000
#define N_EDGES 800000
#define N_TOT   (N_EDGES + N_NODES)
#define N_GRAPHS 256
#define F_IN 310
#define KP1 320          // F_IN padded to multiple of 32
#define CH 256
#define HID 128
#define DEG_CAP 128      // per-wave LDS edge cache (avg deg ~17; P(deg>128) ~ 0)

typedef __attribute__((ext_vector_type(8))) short short8;
typedef __attribute__((ext_vector_type(4))) float f32x4;
typedef unsigned short ushort_t;

__device__ __forceinline__ float selu_f(float x) {
    const float scale = 1.0507009873554805f;
    const float alpha = 1.6732632423543772f;
    return x > 0.f ? scale * x : scale * alpha * (expm1f(x));
}

__device__ __forceinline__ ushort_t f32_to_bf16_rne(float f) {
    unsigned u = __float_as_uint(f);
    unsigned rounding = 0x7FFFu + ((u >> 16) & 1u);
    return (ushort_t)((u + rounding) >> 16);
}
__device__ __forceinline__ float bf16_to_f32(ushort_t v) {
    return __uint_as_float(((unsigned)v) << 16);
}

// ---- convert x [N, 310] f32 -> A [N, 320] bf16, float2-vectorized ----------
__global__ __launch_bounds__(256) void convert_pad_x(
        const float* __restrict__ x, ushort_t* __restrict__ A) {
    int i = blockIdx.x * 256 + threadIdx.x;
    if (i >= N_NODES * (KP1 / 2)) return;
    int r = i / (KP1 / 2);
    int c2 = i - r * (KP1 / 2);
    int c = c2 * 2;
    ushort2 o = {0, 0};
    if (c2 < F_IN / 2) {
        float2 v = *(const float2*)(x + (long)r * F_IN + c);
        o.x = f32_to_bf16_rne(v.x);
        o.y = f32_to_bf16_rne(v.y);
    }
    *(ushort2*)(A + (long)r * KP1 + c) = o;
}

// ---- both W -> Wt conversions in ONE kernel --------------------------------
// W1 [310,256] -> W1t [256,320] (padded); W2 [256,256] -> W2t [256,256]
__global__ __launch_bounds__(256) void convert_wt_both(
        const float* __restrict__ W1, ushort_t* __restrict__ W1t,
        const float* __restrict__ W2, ushort_t* __restrict__ W2t) {
    int i = blockIdx.x * blockDim.x + threadIdx.x;
    const int n1 = CH * KP1;
    if (i < n1) {
        int n = i / KP1, k = i % KP1;
        W1t[i] = (k < F_IN) ? f32_to_bf16_rne(W1[(long)k * CH + n]) : 0;
    } else {
        int j = i - n1;
        if (j >= CH * CH) return;
        int n = j / CH, k = j % CH;
        W2t[j] = f32_to_bf16_rne(W2[(long)k * CH + n]);
    }
}

// ------- MFMA GEMM 64x256 tile, 256 thr (1x4 waves of 64x64), 2-phase -------
// C[M,256] = A[M,Kp]bf16 @ Wt[256,Kp]^T -> bf16 + att-scalar epilogue.
// 782 blocks @ 41KB LDS -> 3 resident/CU, ~3.05 blocks/CU total: balanced.
// Wave tile 64x64: 8 ds_read_b128 per 16 MFMA. Double-buffered LDS, glds
// width=16 prefetch before compute, one barrier/K-step. Chunk swizzle c^(r&3)
// on GLOBAL source + same XOR on read (rule #21).
__global__ __launch_bounds__(256) void gemm_bf16_fused(
        const ushort_t* __restrict__ A, const ushort_t* __restrict__ Bt,
        ushort_t* __restrict__ Cb, const float* __restrict__ att_l,
        const float* __restrict__ att_r, float* __restrict__ a_src,
        float* __restrict__ a_dst, int M, int Kp) {
    __shared__ __align__(16) ushort_t As[2][64 * 32];
    __shared__ __align__(16) ushort_t Bs[2][256 * 32];
    __shared__ float s_pl[64], s_pr[64];
    int tid = threadIdx.x;
    int row0 = blockIdx.x * 64;
    int w = tid >> 6, l = tid & 63;       // w = wave = col-block 0..3
    int lr = l & 15, lc = l >> 4;
    f32x4 acc[4][4] = {};

    // staging: lane l -> row l>>2 within a 16-row group, chunk l&3
    int srow = l >> 2;
    int sx = (l & 3) ^ (srow & 3);        // pre-swizzled source chunk
    int garow = row0 + w * 16 + srow; if (garow >= M) garow = M - 1;
    const ushort_t* gA = A + (size_t)garow * Kp + sx * 8;   // A rows w*16+srow
    const ushort_t* gB[4];
#pragma unroll
    for (int g = 0; g < 4; ++g)           // B rows w*64 + g*16 + srow
        gB[g] = Bt + (size_t)(w * 64 + g * 16 + srow) * Kp + sx * 8;
    int nt = Kp >> 5;

    auto stage = [&](int sel, int k0) {
        __builtin_amdgcn_global_load_lds(
            (const __attribute__((address_space(1))) void*)(gA + k0),
            (__attribute__((address_space(3))) void*)(&As[sel][w * 16 * 32]), 16, 0, 0);
#pragma unroll
        for (int g = 0; g < 4; ++g)
            __builtin_amdgcn_global_load_lds(
                (const __attribute__((address_space(1))) void*)(gB[g] + k0),
                (__attribute__((address_space(3))) void*)(&Bs[sel][(w * 64 + g * 16) * 32]), 16, 0, 0);
    };

    stage(0, 0);
    __syncthreads();
    int cur = 0;
    for (int t = 0; t < nt; ++t) {
        if (t + 1 < nt) stage(cur ^ 1, (t + 1) << 5);
        short8 af[4], bf[4];
#pragma unroll
        for (int mi = 0; mi < 4; ++mi) {
            int r = mi * 16 + lr;
            af[mi] = *(const short8*)(&As[cur][r * 32 + ((lc ^ (r & 3)) * 8)]);
        }
#pragma unroll
        for (int ni = 0; ni < 4; ++ni) {
            int r = w * 64 + ni * 16 + lr;
            bf[ni] = *(const short8*)(&Bs[cur][r * 32 + ((lc ^ (r & 3)) * 8)]);
        }
#pragma unroll
        for (int mi = 0; mi < 4; ++mi)
#pragma unroll
            for (int ni = 0; ni < 4; ++ni)
                acc[mi][ni] = __builtin_amdgcn_mfma_f32_16x16x32_bf16(
                    af[mi], bf[ni], acc[mi][ni], 0, 0, 0);
        __syncthreads();
        cur ^= 1;
    }

    // epilogue: C/D col = lane&15, row = (lane>>4)*4 + q
    if (tid < 64) { s_pl[tid] = 0.f; s_pr[tid] = 0.f; }
    __syncthreads();
    float al[4], ar[4];
#pragma unroll
    for (int ni = 0; ni < 4; ++ni) {
        int col = w * 64 + ni * 16 + lr;
        al[ni] = att_l[col];
        ar[ni] = att_r[col];
    }
#pragma unroll
    for (int mi = 0; mi < 4; ++mi) {
        int lrow = mi * 16 + lc * 4;          // local row base (0..63)
#pragma unroll
        for (int q = 0; q < 4; ++q) {
            int grow = row0 + lrow + q;
            float pl = 0.f, pr = 0.f;
#pragma unroll
            for (int ni = 0; ni < 4; ++ni) {
                float v = acc[mi][ni][q];
                pl += v * al[ni];
                pr += v * ar[ni];
                if (grow < M)
                    Cb[(size_t)grow * CH + w * 64 + ni * 16 + lr] = f32_to_bf16_rne(v);
            }
#pragma unroll
            for (int off = 1; off < 16; off <<= 1) {
                pl += __shfl_xor(pl, off);
                pr += __shfl_xor(pr, off);
            }
            if (lr == 0) {
                atomicAdd(&s_pl[lrow + q], pl);
                atomicAdd(&s_pr[lrow + q], pr);
            }
        }
    }
    __syncthreads();
    if (tid < 64 && row0 + tid < M) {
        a_src[row0 + tid] = s_pl[tid];
        a_dst[row0 + tid] = s_pr[tid];
    }
}

// ---------------- CSR build: deg count -> range reserve -> fill -------------
__global__ __launch_bounds__(256) void deg_count(
        const int* __restrict__ ei, int* __restrict__ deg) {
    int eid = blockIdx.x * blockDim.x + threadIdx.x;
    if (eid >= N_TOT) return;
    int d = (eid < N_EDGES) ? ei[N_EDGES + eid] : eid - N_EDGES;
    atomicAdd(&deg[d], 1);
}

__global__ __launch_bounds__(256) void reserve_k(
        const int* __restrict__ deg, int* __restrict__ start,
        int* __restrict__ fillpos, int* __restrict__ cursor, int n) {
    int i = blockIdx.x * blockDim.x + threadIdx.x;
    if (i >= n) return;
    int s = atomicAdd(cursor, deg[i]);
    start[i] = s;
    fillpos[i] = s;
}

__global__ __launch_bounds__(256) void csr_fill(
        const int* __restrict__ ei, int* __restrict__ fillpos,
        int* __restrict__ csr_src) {
    int eid = blockIdx.x * blockDim.x + threadIdx.x;
    if (eid >= N_TOT) return;
    int s, d;
    if (eid < N_EDGES) { s = ei[eid]; d = ei[N_EDGES + eid]; }
    else { s = eid - N_EDGES; d = s; }
    int p = atomicAdd(&fillpos[d], 1);
    csr_src[p] = s;
}

// ---- fused per-dst softmax + bf16 gather-accumulate, 2-pass ---------------
// No-max softmax (shift-invariant; |e| small for this model). Sweep 1 stashes
// (src, exp) in LDS + lane-sum; gather pass 4 ch/lane ushort4, x8 edge unroll.
__global__ __launch_bounds__(256) void gat_aggregate(
        const int* __restrict__ start, const int* __restrict__ deg,
        const int* __restrict__ csr_src,
        const float* __restrict__ a_src, const float* __restrict__ a_dst,
        const ushort_t* __restrict__ h, const float* __restrict__ bias,
        ushort_t* __restrict__ out_bf, int n) {
    __shared__ int   s_idx[4][DEG_CAP];
    __shared__ float s_ex[4][DEG_CAP];
    int wid = threadIdx.x >> 6;
    int lane = threadIdx.x & 63;
    int node = blockIdx.x * 4 + wid;
    if (node >= n) return;
    int s0 = start[node];
    int dg = deg[node];
    float ad = a_dst[node];
    bool cached = (dg <= DEG_CAP);

    float sum = 0.f;
    for (int i = lane; i < dg; i += 64) {
        int s = csr_src[s0 + i];
        float e = a_src[s] + ad;
        e = fmaxf(e, 0.2f * e);
        float ex = __expf(e);
        if (cached) { s_idx[wid][i] = s; s_ex[wid][i] = ex; }
        sum += ex;
    }
#pragma unroll
    for (int off = 32; off > 0; off >>= 1) sum += __shfl_xor(sum, off);
    float inv = 1.f / fmaxf(sum, 1e-16f);

    float4 acc = {0.f, 0.f, 0.f, 0.f};
    if (cached) {
        int i = 0;
        for (; i + 8 <= dg; i += 8) {
            int   si[8];
            float xi[8];
            ushort4 hv[8];
#pragma unroll
            for (int j = 0; j < 8; ++j) {
                si[j] = s_idx[wid][i + j];
                xi[j] = s_ex[wid][i + j] * inv;
            }
#pragma unroll
            for (int j = 0; j < 8; ++j)
                hv[j] = *(const ushort4*)(h + (long)si[j] * CH + lane * 4);
#pragma unroll
            for (int j = 0; j < 8; ++j) {
                acc.x += xi[j] * bf16_to_f32(hv[j].x);
                acc.y += xi[j] * bf16_to_f32(hv[j].y);
                acc.z += xi[j] * bf16_to_f32(hv[j].z);
                acc.w += xi[j] * bf16_to_f32(hv[j].w);
            }
        }
        for (; i + 4 <= dg; i += 4) {
            int sa = s_idx[wid][i],     sb = s_idx[wid][i + 1];
            int sc_ = s_idx[wid][i + 2], sd = s_idx[wid][i + 3];
            float xa = s_ex[wid][i] * inv,     xb = s_ex[wid][i + 1] * inv;
            float xc = s_ex[wid][i + 2] * inv, xd = s_ex[wid][i + 3] * inv;
            ushort4 ha = *(const ushort4*)(h + (long)sa * CH + lane * 4);
            ushort4 hb = *(const ushort4*)(h + (long)sb * CH + lane * 4);
            ushort4 hc = *(const ushort4*)(h + (long)sc_ * CH + lane * 4);
            ushort4 hd = *(const ushort4*)(h + (long)sd * CH + lane * 4);
            acc.x += xa * bf16_to_f32(ha.x) + xb * bf16_to_f32(hb.x)
                   + xc * bf16_to_f32(hc.x) + xd * bf16_to_f32(hd.x);
            acc.y += xa * bf16_to_f32(ha.y) + xb * bf16_to_f32(hb.y)
                   + xc * bf16_to_f32(hc.y) + xd * bf16_to_f32(hd.y);
            acc.z += xa * bf16_to_f32(ha.z) + xb * bf16_to_f32(hb.z)
                   + xc * bf16_to_f32(hc.z) + xd * bf16_to_f32(hd.z);
            acc.w += xa * bf16_to_f32(ha.w) + xb * bf16_to_f32(hb.w)
                   + xc * bf16_to_f32(hc.w) + xd * bf16_to_f32(hd.w);
        }
        for (; i < dg; i++) {
            int s = s_idx[wid][i];
            float xa = s_ex[wid][i] * inv;
            ushort4 hv = *(const ushort4*)(h + (long)s * CH + lane * 4);
            acc.x += xa * bf16_to_f32(hv.x);
            acc.y += xa * bf16_to_f32(hv.y);
            acc.z += xa * bf16_to_f32(hv.z);
            acc.w += xa * bf16_to_f32(hv.w);
        }
    } else {
        for (int i = 0; i < dg; i++) {
            int s = csr_src[s0 + i];
            float e = a_src[s] + ad;
            e = fmaxf(e, 0.2f * e);
            float alpha = __expf(e) * inv;
            ushort4 hv = *(const ushort4*)(h + (long)s * CH + lane * 4);
            acc.x += alpha * bf16_to_f32(hv.x);
            acc.y += alpha * bf16_to_f32(hv.y);
            acc.z += alpha * bf16_to_f32(hv.z);
            acc.w += alpha * bf16_to_f32(hv.w);
        }
    }
    float4 bv = *(const float4*)(bias + lane * 4);
    ushort4 ob;
    ob.x = f32_to_bf16_rne(selu_f(acc.x + bv.x));
    ob.y = f32_to_bf16_rne(selu_f(acc.y + bv.y));
    ob.z = f32_to_bf16_rne(selu_f(acc.z + bv.z));
    ob.w = f32_to_bf16_rne(selu_f(acc.w + bv.w));
    *(ushort4*)(out_bf + (long)node * CH + lane * 4) = ob;
}

// ---- fused pool + head: one block per graph --------------------------------
// pool (bf16 h, sorted batch, binary search) -> selu -> fc1 -> selu -> fc2
// -> log_softmax. No g1 round-trip, one launch instead of two.
__global__ __launch_bounds__(256) void pool_head_kernel(
        const ushort_t* __restrict__ h, const int* __restrict__ batch,
        const float* __restrict__ fc1W, const float* __restrict__ fc1b,
        const float* __restrict__ fc2W, const float* __restrict__ fc2b,
        float* __restrict__ out) {
    __shared__ float row[CH];
    __shared__ float hrow[HID];
    __shared__ float logits[2];
    int g = blockIdx.x;
    int t = threadIdx.x;
    int lo, hi;
    { int a = 0, b = N_NODES;
      while (a < b) { int mid = (a + b) >> 1; if (batch[mid] < g) a = mid + 1; else b = mid; }
      lo = a; }
    { int a = lo, b = N_NODES;
      while (a < b) { int mid = (a + b) >> 1; if (batch[mid] < g + 1) a = mid + 1; else b = mid; }
      hi = a; }
    float a0 = 0.f, a1 = 0.f, a2 = 0.f, a3 = 0.f;
    int i = lo;
    for (; i + 3 < hi; i += 4) {
        a0 += bf16_to_f32(h[(long)i * CH + t]);
        a1 += bf16_to_f32(h[(long)(i + 1) * CH + t]);
        a2 += bf16_to_f32(h[(long)(i + 2) * CH + t]);
        a3 += bf16_to_f32(h[(long)(i + 3) * CH + t]);
    }
    for (; i < hi; i++) a0 += bf16_to_f32(h[(long)i * CH + t]);
    float acc = (a0 + a1) + (a2 + a3);
    float cnt = (float)(hi - lo);
    row[t] = selu_f(acc / fmaxf(cnt, 1.f));
    __syncthreads();
    if (t < HID) {
        float s = fc1b[t];
        for (int k = 0; k < CH; k++) s += row[k] * fc1W[k * HID + t];
        hrow[t] = selu_f(s);
    }
    __syncthreads();
    if (t < 2) {
        float a = fc2b[t];
        for (int k = 0; k < HID; k++) a += hrow[k] * fc2W[k * 2 + t];
        logits[t] = a;
    }
    __syncthreads();
    if (t < 2) {
        float m = fmaxf(logits[0], logits[1]);
        float lse = logf(expf(logits[0] - m) + expf(logits[1] - m)) + m;
        out[g * 2 + t] = logits[t] - lse;
    }
}

extern "C" void kernel_launch(void* const* d_in, const int* in_sizes, int n_in,
                              void* d_out, int out_size, void* d_ws, size_t ws_size,
                              hipStream_t stream) {
    const float* x      = (const float*)d_in[0];
    const int*   ei     = (const int*)d_in[1];
    const int*   batch  = (const int*)d_in[2];
    const float* W1     = (const float*)d_in[3];
    const float* att_l1 = (const float*)d_in[4];
    const float* att_r1 = (const float*)d_in[5];
    const float* b1     = (const float*)d_in[6];
    const float* W2     = (const float*)d_in[7];
    const float* att_l2 = (const float*)d_in[8];
    const float* att_r2 = (const float*)d_in[9];
    const float* b2     = (const float*)d_in[10];
    const float* fc1W   = (const float*)d_in[11];
    const float* fc1b   = (const float*)d_in[12];
    const float* fc2W   = (const float*)d_in[13];
    const float* fc2b   = (const float*)d_in[14];
    float* out = (float*)d_out;

    char* ws = (char*)d_ws;
    size_t off = 0;
    auto alloc = [&](size_t bytes) {
        void* p = ws + off;
        off += (bytes + 255) & ~(size_t)255;
        return p;
    };
    ushort_t* Ab     = (ushort_t*)alloc((size_t)N_NODES * KP1 * 2);
    ushort_t* Hb1    = (ushort_t*)alloc((size_t)N_NODES * CH * 2);   // GEMM1 out; reused as agg2 out
    ushort_t* Zb2    = (ushort_t*)alloc((size_t)N_NODES * CH * 2);   // agg1 out = GEMM2 in
    ushort_t* Hb2    = (ushort_t*)alloc((size_t)N_NODES * CH * 2);   // GEMM2 out
    ushort_t* W1t    = (ushort_t*)alloc((size_t)CH * KP1 * 2);
    ushort_t* W2t    = (ushort_t*)alloc((size_t)CH * CH * 2);
    float*    a_src  = (float*)alloc((size_t)N_NODES * 4);
    float*    a_dst  = (float*)alloc((size_t)N_NODES * 4);
    int*      deg    = (int*)alloc((size_t)N_NODES * 4);   // cursor directly after
    int*      cursor = (int*)alloc(256);
    int*      startA = (int*)alloc((size_t)N_NODES * 4);
    int*      fillpos= (int*)alloc((size_t)N_NODES * 4);
    int*      csr_src= (int*)alloc((size_t)N_TOT * 4);

    size_t deg_pad = ((size_t)N_NODES * 4 + 255) & ~(size_t)255;

    dim3 blk(256);
    int gemm_grid = (N_NODES + 63) / 64;        // 782 blocks, 256 thr each
    int conv_grid = (N_NODES * (KP1 / 2) + 255) / 256;
    int wt_grid   = (CH * KP1 + CH * CH + 255) / 256;
    int edge_grid = (N_TOT + 255) / 256;
    int node_grid = (N_NODES + 255) / 256;
    int agg_grid  = (N_NODES + 3) / 4;

    // ---------------- input conversions + CSR build ----------------
    convert_pad_x<<<conv_grid, blk, 0, stream>>>(x, Ab);
    convert_wt_both<<<wt_grid, blk, 0, stream>>>(W1, W1t, W2, W2t);
    hipMemsetAsync(deg, 0, deg_pad + 4, stream);          // deg + cursor
    deg_count<<<edge_grid, blk, 0, stream>>>(ei, deg);
    reserve_k<<<node_grid, blk, 0, stream>>>(deg, startA, fillpos, cursor, N_NODES);
    csr_fill<<<edge_grid, blk, 0, stream>>>(ei, fillpos, csr_src);

    // ---------------- Layer 1 ----------------
    gemm_bf16_fused<<<gemm_grid, blk, 0, stream>>>(Ab, W1t, Hb1, att_l1, att_r1,
                                                   a_src, a_dst, N_NODES, KP1);
    gat_aggregate<<<agg_grid, blk, 0, stream>>>(startA, deg, csr_src, a_src, a_dst,
                                                Hb1, b1, Zb2, N_NODES);

    // ---------------- Layer 2 ----------------
    gemm_bf16_fused<<<gemm_grid, blk, 0, stream>>>(Zb2, W2t, Hb2, att_l2, att_r2,
                                                   a_src, a_dst, N_NODES, CH);
    gat_aggregate<<<agg_grid, blk, 0, stream>>>(startA, deg, csr_src, a_src, a_dst,
                                                Hb2, b2, Hb1, N_NODES);

    // ---------------- Pool + head (fused) ----------------
    pool_head_kernel<<<N_GRAPHS, blk, 0, stream>>>(Hb1, batch, fc1W, fc1b,
                                                   fc2W, fc2b, out);
}

// Round 11
// 323.412 us; speedup vs baseline: 1.0297x; 1.0297x over previous
//
#include <hip/hip_runtime.h>
#include <hip/hip_bf16.h>

#define N_NODES 50000
#define N_EDGES 800000
#define N_TOT   (N_EDGES + N_NODES)
#define N_GRAPHS 256
#define F_IN 310
#define KP1 320          // F_IN padded to multiple of 32
#define CH 256
#define HID 128
#define DEG_CAP 128      // per-wave LDS edge cache (avg deg ~17; P(deg>128) ~ 0)

typedef __attribute__((ext_vector_type(8))) short short8;
typedef __attribute__((ext_vector_type(4))) float f32x4;
typedef unsigned short ushort_t;

__device__ __forceinline__ float selu_f(float x) {
    const float scale = 1.0507009873554805f;
    const float alpha = 1.6732632423543772f;
    return x > 0.f ? scale * x : scale * alpha * (expm1f(x));
}

__device__ __forceinline__ ushort_t f32_to_bf16_rne(float f) {
    unsigned u = __float_as_uint(f);
    unsigned rounding = 0x7FFFu + ((u >> 16) & 1u);
    return (ushort_t)((u + rounding) >> 16);
}
__device__ __forceinline__ float bf16_to_f32(ushort_t v) {
    return __uint_as_float(((unsigned)v) << 16);
}

// ---- both W -> Wt conversions in ONE kernel --------------------------------
__global__ __launch_bounds__(256) void convert_wt_both(
        const float* __restrict__ W1, ushort_t* __restrict__ W1t,
        const float* __restrict__ W2, ushort_t* __restrict__ W2t) {
    int i = blockIdx.x * blockDim.x + threadIdx.x;
    const int n1 = CH * KP1;
    if (i < n1) {
        int n = i / KP1, k = i % KP1;
        W1t[i] = (k < F_IN) ? f32_to_bf16_rne(W1[(long)k * CH + n]) : 0;
    } else {
        int j = i - n1;
        if (j >= CH * CH) return;
        int n = j / CH, k = j % CH;
        W2t[j] = f32_to_bf16_rne(W2[(long)k * CH + n]);
    }
}

// ------- MFMA GEMM 64x256 tile, 256 thr (4 waves of 64x64), 2-phase ---------
// C[M,256] = A @ Wt^T -> bf16 + att-scalar epilogue.
// AF32=1: A is f32 [M,310], reg-staged (float2 load -> cvt -> swizzled
//         ds_write_b128) -- fuses the x->bf16 conversion into GEMM1.
// AF32=0: A is bf16 [M,Kp], async glds staged.
// B always glds width=16, pre-swizzled global source + same XOR on read.
template<int AF32>
__global__ __launch_bounds__(256) void gemm_bf16_fused_t(
        const void* __restrict__ Asrc, const ushort_t* __restrict__ Bt,
        ushort_t* __restrict__ Cb, const float* __restrict__ att_l,
        const float* __restrict__ att_r, float* __restrict__ a_srcv,
        float* __restrict__ a_dstv, int M, int Kp) {
    __shared__ __align__(16) ushort_t As[2][64 * 32];
    __shared__ __align__(16) ushort_t Bs[2][256 * 32];
    __shared__ float s_pl[64], s_pr[64];
    int tid = threadIdx.x;
    int row0 = blockIdx.x * 64;
    int w = tid >> 6, l = tid & 63;       // wave w = output col-block
    int lr = l & 15, lc = l >> 4;
    f32x4 acc[4][4] = {};

    int srow = l >> 2;                    // 0..15
    int sc = l & 3;
    int sx = sc ^ (srow & 3);             // pre-swizzled chunk
    int garow = row0 + w * 16 + srow; if (garow >= M) garow = M - 1;
    const ushort_t* gB[4];
#pragma unroll
    for (int g = 0; g < 4; ++g)
        gB[g] = Bt + (size_t)(w * 64 + g * 16 + srow) * Kp + sx * 8;
    int nt = Kp >> 5;

    const ushort_t* gA = nullptr;
    const float* xrow = nullptr;
    if (AF32) xrow = (const float*)Asrc + (size_t)garow * F_IN;
    else      gA = (const ushort_t*)Asrc + (size_t)garow * Kp + sx * 8;

    auto stageB = [&](int sel, int k0) {
#pragma unroll
        for (int g = 0; g < 4; ++g)
            __builtin_amdgcn_global_load_lds(
                (const __attribute__((address_space(1))) void*)(gB[g] + k0),
                (__attribute__((address_space(3))) void*)(&Bs[sel][(w * 64 + g * 16) * 32]), 16, 0, 0);
    };
    auto stageA_glds = [&](int sel, int k0) {
        __builtin_amdgcn_global_load_lds(
            (const __attribute__((address_space(1))) void*)(gA + k0),
            (__attribute__((address_space(3))) void*)(&As[sel][w * 16 * 32]), 16, 0, 0);
    };
    float va[8];
    auto loadA_f32 = [&](int k0) {
        int kc = k0 + sc * 8;
        if (kc + 8 <= F_IN) {              // x rows are 8B-aligned: float2 ok
#pragma unroll
            for (int j = 0; j < 4; ++j) {
                float2 p = *(const float2*)(xrow + kc + j * 2);
                va[j * 2] = p.x; va[j * 2 + 1] = p.y;
            }
        } else {                           // K tail (cols >= 310 -> 0)
#pragma unroll
            for (int j = 0; j < 8; ++j)
                va[j] = (kc + j < F_IN) ? xrow[kc + j] : 0.f;
        }
    };
    auto writeA = [&](int sel) {
        short8 s;
#pragma unroll
        for (int j = 0; j < 8; ++j) s[j] = (short)f32_to_bf16_rne(va[j]);
        *(short8*)(&As[sel][(w * 16 + srow) * 32 + sx * 8]) = s;
    };

    if (AF32) loadA_f32(0); else stageA_glds(0, 0);
    stageB(0, 0);
    if (AF32) writeA(0);
    __syncthreads();
    int cur = 0;
    for (int t = 0; t < nt; ++t) {
        int k1 = (t + 1) << 5;
        if (t + 1 < nt) {
            if (AF32) loadA_f32(k1); else stageA_glds(cur ^ 1, k1);
            stageB(cur ^ 1, k1);
        }
        short8 af[4], bfv[4];
#pragma unroll
        for (int mi = 0; mi < 4; ++mi) {
            int r = mi * 16 + lr;
            af[mi] = *(const short8*)(&As[cur][r * 32 + ((lc ^ (r & 3)) * 8)]);
        }
#pragma unroll
        for (int ni = 0; ni < 4; ++ni) {
            int r = w * 64 + ni * 16 + lr;
            bfv[ni] = *(const short8*)(&Bs[cur][r * 32 + ((lc ^ (r & 3)) * 8)]);
        }
#pragma unroll
        for (int mi = 0; mi < 4; ++mi)
#pragma unroll
            for (int ni = 0; ni < 4; ++ni)
                acc[mi][ni] = __builtin_amdgcn_mfma_f32_16x16x32_bf16(
                    af[mi], bfv[ni], acc[mi][ni], 0, 0, 0);
        if (AF32 && t + 1 < nt) writeA(cur ^ 1);
        __syncthreads();
        cur ^= 1;
    }

    // epilogue: C/D col = lane&15, row = (lane>>4)*4 + q
    if (tid < 64) { s_pl[tid] = 0.f; s_pr[tid] = 0.f; }
    __syncthreads();
    float al[4], ar[4];
#pragma unroll
    for (int ni = 0; ni < 4; ++ni) {
        int col = w * 64 + ni * 16 + lr;
        al[ni] = att_l[col];
        ar[ni] = att_r[col];
    }
#pragma unroll
    for (int mi = 0; mi < 4; ++mi) {
        int lrow = mi * 16 + lc * 4;
#pragma unroll
        for (int q = 0; q < 4; ++q) {
            int grow = row0 + lrow + q;
            float pl = 0.f, pr = 0.f;
#pragma unroll
            for (int ni = 0; ni < 4; ++ni) {
                float v = acc[mi][ni][q];
                pl += v * al[ni];
                pr += v * ar[ni];
                if (grow < M)
                    Cb[(size_t)grow * CH + w * 64 + ni * 16 + lr] = f32_to_bf16_rne(v);
            }
#pragma unroll
            for (int off = 1; off < 16; off <<= 1) {
                pl += __shfl_xor(pl, off);
                pr += __shfl_xor(pr, off);
            }
            if (lr == 0) {
                atomicAdd(&s_pl[lrow + q], pl);
                atomicAdd(&s_pr[lrow + q], pr);
            }
        }
    }
    __syncthreads();
    if (tid < 64 && row0 + tid < M) {
        a_srcv[row0 + tid] = s_pl[tid];
        a_dstv[row0 + tid] = s_pr[tid];
    }
}

// ---------------- CSR build: deg count -> range reserve -> fill -------------
__global__ __launch_bounds__(256) void deg_count(
        const int* __restrict__ ei, int* __restrict__ deg) {
    int eid = blockIdx.x * blockDim.x + threadIdx.x;
    if (eid >= N_TOT) return;
    int d = (eid < N_EDGES) ? ei[N_EDGES + eid] : eid - N_EDGES;
    atomicAdd(&deg[d], 1);
}

__global__ __launch_bounds__(256) void reserve_k(
        const int* __restrict__ deg, int* __restrict__ start,
        int* __restrict__ fillpos, int* __restrict__ cursor, int n) {
    int i = blockIdx.x * blockDim.x + threadIdx.x;
    if (i >= n) return;
    int s = atomicAdd(cursor, deg[i]);
    start[i] = s;
    fillpos[i] = s;
}

__global__ __launch_bounds__(256) void csr_fill(
        const int* __restrict__ ei, int* __restrict__ fillpos,
        int* __restrict__ csr_src) {
    int eid = blockIdx.x * blockDim.x + threadIdx.x;
    if (eid >= N_TOT) return;
    int s, d;
    if (eid < N_EDGES) { s = ei[eid]; d = ei[N_EDGES + eid]; }
    else { s = eid - N_EDGES; d = s; }
    int p = atomicAdd(&fillpos[d], 1);
    csr_src[p] = s;
}

// ---- fused per-dst softmax + bf16 gather-accumulate, 2-pass ---------------
// No-max softmax (shift-invariant; |e| small for this model). Sweep 1 stashes
// (src, exp) in LDS + lane-sum; gather pass 4 ch/lane ushort4, x8 edge unroll.
__global__ __launch_bounds__(256) void gat_aggregate(
        const int* __restrict__ start, const int* __restrict__ deg,
        const int* __restrict__ csr_src,
        const float* __restrict__ a_src, const float* __restrict__ a_dst,
        const ushort_t* __restrict__ h, const float* __restrict__ bias,
        ushort_t* __restrict__ out_bf, int n) {
    __shared__ int   s_idx[4][DEG_CAP];
    __shared__ float s_ex[4][DEG_CAP];
    int wid = threadIdx.x >> 6;
    int lane = threadIdx.x & 63;
    int node = blockIdx.x * 4 + wid;
    if (node >= n) return;
    int s0 = start[node];
    int dg = deg[node];
    float ad = a_dst[node];
    bool cached = (dg <= DEG_CAP);

    float sum = 0.f;
    for (int i = lane; i < dg; i += 64) {
        int s = csr_src[s0 + i];
        float e = a_src[s] + ad;
        e = fmaxf(e, 0.2f * e);
        float ex = __expf(e);
        if (cached) { s_idx[wid][i] = s; s_ex[wid][i] = ex; }
        sum += ex;
    }
#pragma unroll
    for (int off = 32; off > 0; off >>= 1) sum += __shfl_xor(sum, off);
    float inv = 1.f / fmaxf(sum, 1e-16f);

    float4 acc = {0.f, 0.f, 0.f, 0.f};
    if (cached) {
        int i = 0;
        for (; i + 8 <= dg; i += 8) {
            int   si[8];
            float xi[8];
            ushort4 hv[8];
#pragma unroll
            for (int j = 0; j < 8; ++j) {
                si[j] = s_idx[wid][i + j];
                xi[j] = s_ex[wid][i + j] * inv;
            }
#pragma unroll
            for (int j = 0; j < 8; ++j)
                hv[j] = *(const ushort4*)(h + (long)si[j] * CH + lane * 4);
#pragma unroll
            for (int j = 0; j < 8; ++j) {
                acc.x += xi[j] * bf16_to_f32(hv[j].x);
                acc.y += xi[j] * bf16_to_f32(hv[j].y);
                acc.z += xi[j] * bf16_to_f32(hv[j].z);
                acc.w += xi[j] * bf16_to_f32(hv[j].w);
            }
        }
        for (; i + 4 <= dg; i += 4) {
            int sa = s_idx[wid][i],     sb = s_idx[wid][i + 1];
            int sc_ = s_idx[wid][i + 2], sd = s_idx[wid][i + 3];
            float xa = s_ex[wid][i] * inv,     xb = s_ex[wid][i + 1] * inv;
            float xc = s_ex[wid][i + 2] * inv, xd = s_ex[wid][i + 3] * inv;
            ushort4 ha = *(const ushort4*)(h + (long)sa * CH + lane * 4);
            ushort4 hb = *(const ushort4*)(h + (long)sb * CH + lane * 4);
            ushort4 hc = *(const ushort4*)(h + (long)sc_ * CH + lane * 4);
            ushort4 hd = *(const ushort4*)(h + (long)sd * CH + lane * 4);
            acc.x += xa * bf16_to_f32(ha.x) + xb * bf16_to_f32(hb.x)
                   + xc * bf16_to_f32(hc.x) + xd * bf16_to_f32(hd.x);
            acc.y += xa * bf16_to_f32(ha.y) + xb * bf16_to_f32(hb.y)
                   + xc * bf16_to_f32(hc.y) + xd * bf16_to_f32(hd.y);
            acc.z += xa * bf16_to_f32(ha.z) + xb * bf16_to_f32(hb.z)
                   + xc * bf16_to_f32(hc.z) + xd * bf16_to_f32(hd.z);
            acc.w += xa * bf16_to_f32(ha.w) + xb * bf16_to_f32(hb.w)
                   + xc * bf16_to_f32(hc.w) + xd * bf16_to_f32(hd.w);
        }
        for (; i < dg; i++) {
            int s = s_idx[wid][i];
            float xa = s_ex[wid][i] * inv;
            ushort4 hv = *(const ushort4*)(h + (long)s * CH + lane * 4);
            acc.x += xa * bf16_to_f32(hv.x);
            acc.y += xa * bf16_to_f32(hv.y);
            acc.z += xa * bf16_to_f32(hv.z);
            acc.w += xa * bf16_to_f32(hv.w);
        }
    } else {
        for (int i = 0; i < dg; i++) {
            int s = csr_src[s0 + i];
            float e = a_src[s] + ad;
            e = fmaxf(e, 0.2f * e);
            float alpha = __expf(e) * inv;
            ushort4 hv = *(const ushort4*)(h + (long)s * CH + lane * 4);
            acc.x += alpha * bf16_to_f32(hv.x);
            acc.y += alpha * bf16_to_f32(hv.y);
            acc.z += alpha * bf16_to_f32(hv.z);
            acc.w += alpha * bf16_to_f32(hv.w);
        }
    }
    float4 bv = *(const float4*)(bias + lane * 4);
    ushort4 ob;
    ob.x = f32_to_bf16_rne(selu_f(acc.x + bv.x));
    ob.y = f32_to_bf16_rne(selu_f(acc.y + bv.y));
    ob.z = f32_to_bf16_rne(selu_f(acc.z + bv.z));
    ob.w = f32_to_bf16_rne(selu_f(acc.w + bv.w));
    *(ushort4*)(out_bf + (long)node * CH + lane * 4) = ob;
}

// ---- fused pool + head: one block (1024 thr) per graph ---------------------
// pool: 4 row-quarters x 256 ch, LDS-combined; fc1: 8 k-segments x 128 out,
// LDS-reduced; fc2 + log_softmax.
__global__ __launch_bounds__(1024) void pool_head_kernel(
        const ushort_t* __restrict__ h, const int* __restrict__ batch,
        const float* __restrict__ fc1W, const float* __restrict__ fc1b,
        const float* __restrict__ fc2W, const float* __restrict__ fc2b,
        float* __restrict__ out) {
    __shared__ float part[4][CH];
    __shared__ float row[CH];
    __shared__ float part2[8][HID];
    __shared__ float hrow[HID];
    __shared__ float logits[2];
    int g = blockIdx.x;
    int tid = threadIdx.x;
    int t = tid & 255;
    int quad = tid >> 8;              // 0..3
    int lo, hi;
    { int a = 0, b = N_NODES;
      while (a < b) { int mid = (a + b) >> 1; if (batch[mid] < g) a = mid + 1; else b = mid; }
      lo = a; }
    { int a = lo, b = N_NODES;
      while (a < b) { int mid = (a + b) >> 1; if (batch[mid] < g + 1) a = mid + 1; else b = mid; }
      hi = a; }
    float a0 = 0.f, a1 = 0.f;
    int i = lo + quad;
    for (; i + 4 < hi; i += 8) {
        a0 += bf16_to_f32(h[(long)i * CH + t]);
        a1 += bf16_to_f32(h[(long)(i + 4) * CH + t]);
    }
    for (; i < hi; i += 4) a0 += bf16_to_f32(h[(long)i * CH + t]);
    part[quad][t] = a0 + a1;
    __syncthreads();
    if (quad == 0) {
        float cnt = (float)(hi - lo);
        float acc = (part[0][t] + part[1][t]) + (part[2][t] + part[3][t]);
        row[t] = selu_f(acc / fmaxf(cnt, 1.f));
    }
    __syncthreads();
    {   // fc1: tid -> (seg = tid>>7 in 0..7, o = tid&127)
        int o = tid & 127;
        int seg = tid >> 7;
        float s = 0.f;
        int k0 = seg * 32;
        for (int k = k0; k < k0 + 32; ++k) s += row[k] * fc1W[k * HID + o];
        part2[seg][o] = s;
    }
    __syncthreads();
    if (tid < HID) {
        float s = fc1b[tid];
#pragma unroll
        for (int j = 0; j < 8; ++j) s += part2[j][tid];
        hrow[tid] = selu_f(s);
    }
    __syncthreads();
    if (tid < 2) {
        float a = fc2b[tid];
        for (int k = 0; k < HID; k++) a += hrow[k] * fc2W[k * 2 + tid];
        logits[tid] = a;
    }
    __syncthreads();
    if (tid < 2) {
        float m = fmaxf(logits[0], logits[1]);
        float lse = logf(expf(logits[0] - m) + expf(logits[1] - m)) + m;
        out[g * 2 + tid] = logits[tid] - lse;
    }
}

extern "C" void kernel_launch(void* const* d_in, const int* in_sizes, int n_in,
                              void* d_out, int out_size, void* d_ws, size_t ws_size,
                              hipStream_t stream) {
    const float* x      = (const float*)d_in[0];
    const int*   ei     = (const int*)d_in[1];
    const int*   batch  = (const int*)d_in[2];
    const float* W1     = (const float*)d_in[3];
    const float* att_l1 = (const float*)d_in[4];
    const float* att_r1 = (const float*)d_in[5];
    const float* b1     = (const float*)d_in[6];
    const float* W2     = (const float*)d_in[7];
    const float* att_l2 = (const float*)d_in[8];
    const float* att_r2 = (const float*)d_in[9];
    const float* b2     = (const float*)d_in[10];
    const float* fc1W   = (const float*)d_in[11];
    const float* fc1b   = (const float*)d_in[12];
    const float* fc2W   = (const float*)d_in[13];
    const float* fc2b   = (const float*)d_in[14];
    float* out = (float*)d_out;

    char* ws = (char*)d_ws;
    size_t off = 0;
    auto alloc = [&](size_t bytes) {
        void* p = ws + off;
        off += (bytes + 255) & ~(size_t)255;
        return p;
    };
    ushort_t* Hb1    = (ushort_t*)alloc((size_t)N_NODES * CH * 2);   // GEMM1 out; reused as agg2 out
    ushort_t* Zb2    = (ushort_t*)alloc((size_t)N_NODES * CH * 2);   // agg1 out = GEMM2 in
    ushort_t* Hb2    = (ushort_t*)alloc((size_t)N_NODES * CH * 2);   // GEMM2 out
    ushort_t* W1t    = (ushort_t*)alloc((size_t)CH * KP1 * 2);
    ushort_t* W2t    = (ushort_t*)alloc((size_t)CH * CH * 2);
    float*    a_src  = (float*)alloc((size_t)N_NODES * 4);
    float*    a_dst  = (float*)alloc((size_t)N_NODES * 4);
    int*      deg    = (int*)alloc((size_t)N_NODES * 4);   // cursor directly after
    int*      cursor = (int*)alloc(256);
    int*      startA = (int*)alloc((size_t)N_NODES * 4);
    int*      fillpos= (int*)alloc((size_t)N_NODES * 4);
    int*      csr_src= (int*)alloc((size_t)N_TOT * 4);

    size_t deg_pad = ((size_t)N_NODES * 4 + 255) & ~(size_t)255;

    dim3 blk(256);
    int gemm_grid = (N_NODES + 63) / 64;        // 782 blocks, 256 thr each
    int wt_grid   = (CH * KP1 + CH * CH + 255) / 256;
    int edge_grid = (N_TOT + 255) / 256;
    int node_grid = (N_NODES + 255) / 256;
    int agg_grid  = (N_NODES + 3) / 4;

    // ---------------- weight conversion + CSR build ----------------
    convert_wt_both<<<wt_grid, blk, 0, stream>>>(W1, W1t, W2, W2t);
    hipMemsetAsync(deg, 0, deg_pad + 4, stream);          // deg + cursor
    deg_count<<<edge_grid, blk, 0, stream>>>(ei, deg);
    reserve_k<<<node_grid, blk, 0, stream>>>(deg, startA, fillpos, cursor, N_NODES);
    csr_fill<<<edge_grid, blk, 0, stream>>>(ei, fillpos, csr_src);

    // ---------------- Layer 1 (x conversion fused into GEMM) ----------------
    gemm_bf16_fused_t<1><<<gemm_grid, blk, 0, stream>>>(x, W1t, Hb1, att_l1, att_r1,
                                                        a_src, a_dst, N_NODES, KP1);
    gat_aggregate<<<agg_grid, blk, 0, stream>>>(startA, deg, csr_src, a_src, a_dst,
                                                Hb1, b1, Zb2, N_NODES);

    // ---------------- Layer 2 ----------------
    gemm_bf16_fused_t<0><<<gemm_grid, blk, 0, stream>>>(Zb2, W2t, Hb2, att_l2, att_r2,
                                                        a_src, a_dst, N_NODES, CH);
    gat_aggregate<<<agg_grid, blk, 0, stream>>>(startA, deg, csr_src, a_src, a_dst,
                                                Hb2, b2, Hb1, N_NODES);

    // ---------------- Pool + head (fused, 1024 thr/graph) ----------------
    pool_head_kernel<<<N_GRAPHS, dim3(1024), 0, stream>>>(Hb1, batch, fc1W, fc1b,
                                                          fc2W, fc2b, out);
}

// Round 12
// 313.549 us; speedup vs baseline: 1.0621x; 1.0315x over previous
//
#include <hip/hip_runtime.h>
#include <hip/hip_bf16.h>

#define N_NODES 50000
#define N_EDGES 800000
#define N_TOT   (N_EDGES + N_NODES)
#define N_GRAPHS 256
#define F_IN 310
#define KP1 320          // F_IN padded to multiple of 32
#define CH 256
#define HID 128

typedef __attribute__((ext_vector_type(8))) short short8;
typedef __attribute__((ext_vector_type(4))) float f32x4;
typedef unsigned short ushort_t;

__device__ __forceinline__ float selu_f(float x) {
    const float scale = 1.0507009873554805f;
    const float alpha = 1.6732632423543772f;
    return x > 0.f ? scale * x : scale * alpha * (expm1f(x));
}

__device__ __forceinline__ ushort_t f32_to_bf16_rne(float f) {
    unsigned u = __float_as_uint(f);
    unsigned rounding = 0x7FFFu + ((u >> 16) & 1u);
    return (ushort_t)((u + rounding) >> 16);
}
__device__ __forceinline__ float bf16_to_f32(ushort_t v) {
    return __uint_as_float(((unsigned)v) << 16);
}

// ---- W conversions + deg_count fused into one launch -----------------------
// blocks [0, WT_BLKS): W1/W2 -> transposed bf16; blocks [WT_BLKS, ...): deg.
#define WT_BLKS ((CH * KP1 + CH * CH + 255) / 256)
__global__ __launch_bounds__(256) void convert_wt_deg(
        const float* __restrict__ W1, ushort_t* __restrict__ W1t,
        const float* __restrict__ W2, ushort_t* __restrict__ W2t,
        const int* __restrict__ ei, int* __restrict__ deg) {
    int b = blockIdx.x;
    if (b < WT_BLKS) {
        int i = b * 256 + threadIdx.x;
        const int n1 = CH * KP1;
        if (i < n1) {
            int n = i / KP1, k = i % KP1;
            W1t[i] = (k < F_IN) ? f32_to_bf16_rne(W1[(long)k * CH + n]) : 0;
        } else {
            int j = i - n1;
            if (j >= CH * CH) return;
            int n = j / CH, k = j % CH;
            W2t[j] = f32_to_bf16_rne(W2[(long)k * CH + n]);
        }
    } else {
        int eid = (b - WT_BLKS) * 256 + threadIdx.x;
        if (eid >= N_TOT) return;
        int d = (eid < N_EDGES) ? ei[N_EDGES + eid] : eid - N_EDGES;
        atomicAdd(&deg[d], 1);
    }
}

// ------- MFMA GEMM 64x256 tile, 256 thr (4 waves of 64x64), 2-phase ---------
// LDS exactly 40KB (epilogue reuses As) + __launch_bounds__(256,4)
// -> 4 blocks/CU, 1024 co-resident >= 782 grid: single-round makespan.
// AF32=1: A is f32 [M,310] reg-staged (fused x->bf16). AF32=0: A bf16 glds.
// B always glds width=16; chunk swizzle c^(r&3) pre-applied on the GLOBAL
// source, same XOR on read (rule #21).
template<int AF32>
__global__ __launch_bounds__(256, 4) void gemm_bf16_fused_t(
        const void* __restrict__ Asrc, const ushort_t* __restrict__ Bt,
        ushort_t* __restrict__ Cb, const float* __restrict__ att_l,
        const float* __restrict__ att_r, float* __restrict__ a_srcv,
        float* __restrict__ a_dstv, int M, int Kp) {
    __shared__ __align__(16) ushort_t As[2][64 * 32];   //  8 KB
    __shared__ __align__(16) ushort_t Bs[2][256 * 32];  // 32 KB  -> 40 KB total
    int tid = threadIdx.x;
    int row0 = blockIdx.x * 64;
    int w = tid >> 6, l = tid & 63;       // wave w = output col-block
    int lr = l & 15, lc = l >> 4;
    f32x4 acc[4][4] = {};

    int srow = l >> 2;                    // 0..15
    int sc = l & 3;
    int sx = sc ^ (srow & 3);             // pre-swizzled chunk
    int garow = row0 + w * 16 + srow; if (garow >= M) garow = M - 1;
    const ushort_t* gB[4];
#pragma unroll
    for (int g = 0; g < 4; ++g)
        gB[g] = Bt + (size_t)(w * 64 + g * 16 + srow) * Kp + sx * 8;
    int nt = Kp >> 5;

    const ushort_t* gA = nullptr;
    const float* xrow = nullptr;
    if (AF32) xrow = (const float*)Asrc + (size_t)garow * F_IN;
    else      gA = (const ushort_t*)Asrc + (size_t)garow * Kp + sx * 8;

    auto stageB = [&](int sel, int k0) {
#pragma unroll
        for (int g = 0; g < 4; ++g)
            __builtin_amdgcn_global_load_lds(
                (const __attribute__((address_space(1))) void*)(gB[g] + k0),
                (__attribute__((address_space(3))) void*)(&Bs[sel][(w * 64 + g * 16) * 32]), 16, 0, 0);
    };
    auto stageA_glds = [&](int sel, int k0) {
        __builtin_amdgcn_global_load_lds(
            (const __attribute__((address_space(1))) void*)(gA + k0),
            (__attribute__((address_space(3))) void*)(&As[sel][w * 16 * 32]), 16, 0, 0);
    };
    float va[8];
    auto loadA_f32 = [&](int k0) {
        int kc = k0 + sc * 8;
        if (kc + 8 <= F_IN) {              // x rows are 8B-aligned: float2 ok
#pragma unroll
            for (int j = 0; j < 4; ++j) {
                float2 p = *(const float2*)(xrow + kc + j * 2);
                va[j * 2] = p.x; va[j * 2 + 1] = p.y;
            }
        } else {                           // K tail (cols >= 310 -> 0)
#pragma unroll
            for (int j = 0; j < 8; ++j)
                va[j] = (kc + j < F_IN) ? xrow[kc + j] : 0.f;
        }
    };
    auto writeA = [&](int sel) {
        short8 s;
#pragma unroll
        for (int j = 0; j < 8; ++j) s[j] = (short)f32_to_bf16_rne(va[j]);
        *(short8*)(&As[sel][(w * 16 + srow) * 32 + sx * 8]) = s;
    };

    if (AF32) loadA_f32(0); else stageA_glds(0, 0);
    stageB(0, 0);
    if (AF32) writeA(0);
    __syncthreads();
    int cur = 0;
    for (int t = 0; t < nt; ++t) {
        int k1 = (t + 1) << 5;
        if (t + 1 < nt) {
            if (AF32) loadA_f32(k1); else stageA_glds(cur ^ 1, k1);
            stageB(cur ^ 1, k1);
        }
        short8 af[4], bfv[4];
#pragma unroll
        for (int mi = 0; mi < 4; ++mi) {
            int r = mi * 16 + lr;
            af[mi] = *(const short8*)(&As[cur][r * 32 + ((lc ^ (r & 3)) * 8)]);
        }
#pragma unroll
        for (int ni = 0; ni < 4; ++ni) {
            int r = w * 64 + ni * 16 + lr;
            bfv[ni] = *(const short8*)(&Bs[cur][r * 32 + ((lc ^ (r & 3)) * 8)]);
        }
#pragma unroll
        for (int mi = 0; mi < 4; ++mi)
#pragma unroll
            for (int ni = 0; ni < 4; ++ni)
                acc[mi][ni] = __builtin_amdgcn_mfma_f32_16x16x32_bf16(
                    af[mi], bfv[ni], acc[mi][ni], 0, 0, 0);
        if (AF32 && t + 1 < nt) writeA(cur ^ 1);
        __syncthreads();
        cur ^= 1;
    }

    // epilogue: reuse As (free after the loop's final barrier) as scratch
    float* s_pl = (float*)&As[0][0];      // 64 floats
    float* s_pr = s_pl + 64;              // 64 floats (within the 8KB region)
    if (tid < 128) s_pl[tid] = 0.f;       // zeros both arrays
    __syncthreads();
    float al[4], ar[4];
#pragma unroll
    for (int ni = 0; ni < 4; ++ni) {
        int col = w * 64 + ni * 16 + lr;
        al[ni] = att_l[col];
        ar[ni] = att_r[col];
    }
#pragma unroll
    for (int mi = 0; mi < 4; ++mi) {
        int lrow = mi * 16 + lc * 4;
#pragma unroll
        for (int q = 0; q < 4; ++q) {
            int grow = row0 + lrow + q;
            float pl = 0.f, pr = 0.f;
#pragma unroll
            for (int ni = 0; ni < 4; ++ni) {
                float v = acc[mi][ni][q];
                pl += v * al[ni];
                pr += v * ar[ni];
                if (grow < M)
                    Cb[(size_t)grow * CH + w * 64 + ni * 16 + lr] = f32_to_bf16_rne(v);
            }
#pragma unroll
            for (int off = 1; off < 16; off <<= 1) {
                pl += __shfl_xor(pl, off);
                pr += __shfl_xor(pr, off);
            }
            if (lr == 0) {
                atomicAdd(&s_pl[lrow + q], pl);
                atomicAdd(&s_pr[lrow + q], pr);
            }
        }
    }
    __syncthreads();
    if (tid < 64 && row0 + tid < M) {
        a_srcv[row0 + tid] = s_pl[tid];
        a_dstv[row0 + tid] = s_pr[tid];
    }
}

// ---------------- CSR build: range reserve -> fill --------------------------
__global__ __launch_bounds__(256) void reserve_k(
        const int* __restrict__ deg, int* __restrict__ start,
        int* __restrict__ fillpos, int* __restrict__ cursor, int n) {
    int i = blockIdx.x * blockDim.x + threadIdx.x;
    if (i >= n) return;
    int s = atomicAdd(cursor, deg[i]);
    start[i] = s;
    fillpos[i] = s;
}

__global__ __launch_bounds__(256) void csr_fill(
        const int* __restrict__ ei, int* __restrict__ fillpos,
        int* __restrict__ csr_src) {
    int eid = blockIdx.x * blockDim.x + threadIdx.x;
    if (eid >= N_TOT) return;
    int s, d;
    if (eid < N_EDGES) { s = ei[eid]; d = ei[N_EDGES + eid]; }
    else { s = eid - N_EDGES; d = s; }
    int p = atomicAdd(&fillpos[d], 1);
    csr_src[p] = s;
}

// ---- fused per-dst GAT aggregate: SINGLE edge pass -------------------------
// inv applied at the end: out = (sum_e ex*h[src]) * inv  (valid: no max shift).
// Per 64-edge chunk: lane-parallel (src, ex) into REGISTERS (+ per-lane sum),
// then gather loop broadcasts via __shfl (no LDS stash, no second sweep);
// 8 h-row gathers in flight.
__global__ __launch_bounds__(256) void gat_aggregate(
        const int* __restrict__ start, const int* __restrict__ deg,
        const int* __restrict__ csr_src,
        const float* __restrict__ a_src, const float* __restrict__ a_dst,
        const ushort_t* __restrict__ h, const float* __restrict__ bias,
        ushort_t* __restrict__ out_bf, int n) {
    int wid = threadIdx.x >> 6;
    int lane = threadIdx.x & 63;
    int node = blockIdx.x * 4 + wid;
    if (node >= n) return;
    int s0 = start[node];
    int dg = deg[node];
    float ad = a_dst[node];

    float sum_l = 0.f;
    float4 acc = {0.f, 0.f, 0.f, 0.f};
    for (int c = 0; c < dg; c += 64) {
        int nc = min(64, dg - c);
        int s_l = 0; float ex_l = 0.f;
        if (lane < nc) {
            s_l = csr_src[s0 + c + lane];
            float e = a_src[s_l] + ad;
            e = fmaxf(e, 0.2f * e);
            ex_l = __expf(e);
            sum_l += ex_l;
        }
        int j = 0;
        for (; j + 8 <= nc; j += 8) {
            int si[8]; float xi[8]; ushort4 hv[8];
#pragma unroll
            for (int k = 0; k < 8; ++k) {
                si[k] = __shfl(s_l, j + k);
                xi[k] = __shfl(ex_l, j + k);
            }
#pragma unroll
            for (int k = 0; k < 8; ++k)
                hv[k] = *(const ushort4*)(h + (long)si[k] * CH + lane * 4);
#pragma unroll
            for (int k = 0; k < 8; ++k) {
                acc.x += xi[k] * bf16_to_f32(hv[k].x);
                acc.y += xi[k] * bf16_to_f32(hv[k].y);
                acc.z += xi[k] * bf16_to_f32(hv[k].z);
                acc.w += xi[k] * bf16_to_f32(hv[k].w);
            }
        }
        for (; j < nc; ++j) {
            int sj = __shfl(s_l, j);
            float xj = __shfl(ex_l, j);
            ushort4 hv = *(const ushort4*)(h + (long)sj * CH + lane * 4);
            acc.x += xj * bf16_to_f32(hv.x);
            acc.y += xj * bf16_to_f32(hv.y);
            acc.z += xj * bf16_to_f32(hv.z);
            acc.w += xj * bf16_to_f32(hv.w);
        }
    }
    float sum = sum_l;
#pragma unroll
    for (int off = 32; off > 0; off >>= 1) sum += __shfl_xor(sum, off);
    float inv = 1.f / fmaxf(sum, 1e-16f);

    float4 bv = *(const float4*)(bias + lane * 4);
    ushort4 ob;
    ob.x = f32_to_bf16_rne(selu_f(acc.x * inv + bv.x));
    ob.y = f32_to_bf16_rne(selu_f(acc.y * inv + bv.y));
    ob.z = f32_to_bf16_rne(selu_f(acc.z * inv + bv.z));
    ob.w = f32_to_bf16_rne(selu_f(acc.w * inv + bv.w));
    *(ushort4*)(out_bf + (long)node * CH + lane * 4) = ob;
}

// ---- fused pool + head: one block (1024 thr) per graph ---------------------
__global__ __launch_bounds__(1024) void pool_head_kernel(
        const ushort_t* __restrict__ h, const int* __restrict__ batch,
        const float* __restrict__ fc1W, const float* __restrict__ fc1b,
        const float* __restrict__ fc2W, const float* __restrict__ fc2b,
        float* __restrict__ out) {
    __shared__ float part[4][CH];
    __shared__ float row[CH];
    __shared__ float part2[8][HID];
    __shared__ float hrow[HID];
    __shared__ float logits[2];
    int g = blockIdx.x;
    int tid = threadIdx.x;
    int t = tid & 255;
    int quad = tid >> 8;              // 0..3
    int lo, hi;
    { int a = 0, b = N_NODES;
      while (a < b) { int mid = (a + b) >> 1; if (batch[mid] < g) a = mid + 1; else b = mid; }
      lo = a; }
    { int a = lo, b = N_NODES;
      while (a < b) { int mid = (a + b) >> 1; if (batch[mid] < g + 1) a = mid + 1; else b = mid; }
      hi = a; }
    float a0 = 0.f, a1 = 0.f;
    int i = lo + quad;
    for (; i + 4 < hi; i += 8) {
        a0 += bf16_to_f32(h[(long)i * CH + t]);
        a1 += bf16_to_f32(h[(long)(i + 4) * CH + t]);
    }
    for (; i < hi; i += 4) a0 += bf16_to_f32(h[(long)i * CH + t]);
    part[quad][t] = a0 + a1;
    __syncthreads();
    if (quad == 0) {
        float cnt = (float)(hi - lo);
        float acc = (part[0][t] + part[1][t]) + (part[2][t] + part[3][t]);
        row[t] = selu_f(acc / fmaxf(cnt, 1.f));
    }
    __syncthreads();
    {   // fc1: tid -> (seg = tid>>7 in 0..7, o = tid&127)
        int o = tid & 127;
        int seg = tid >> 7;
        float s = 0.f;
        int k0 = seg * 32;
        for (int k = k0; k < k0 + 32; ++k) s += row[k] * fc1W[k * HID + o];
        part2[seg][o] = s;
    }
    __syncthreads();
    if (tid < HID) {
        float s = fc1b[tid];
#pragma unroll
        for (int j = 0; j < 8; ++j) s += part2[j][tid];
        hrow[tid] = selu_f(s);
    }
    __syncthreads();
    if (tid < 2) {
        float a = fc2b[tid];
        for (int k = 0; k < HID; k++) a += hrow[k] * fc2W[k * 2 + tid];
        logits[tid] = a;
    }
    __syncthreads();
    if (tid < 2) {
        float m = fmaxf(logits[0], logits[1]);
        float lse = logf(expf(logits[0] - m) + expf(logits[1] - m)) + m;
        out[g * 2 + tid] = logits[tid] - lse;
    }
}

extern "C" void kernel_launch(void* const* d_in, const int* in_sizes, int n_in,
                              void* d_out, int out_size, void* d_ws, size_t ws_size,
                              hipStream_t stream) {
    const float* x      = (const float*)d_in[0];
    const int*   ei     = (const int*)d_in[1];
    const int*   batch  = (const int*)d_in[2];
    const float* W1     = (const float*)d_in[3];
    const float* att_l1 = (const float*)d_in[4];
    const float* att_r1 = (const float*)d_in[5];
    const float* b1     = (const float*)d_in[6];
    const float* W2     = (const float*)d_in[7];
    const float* att_l2 = (const float*)d_in[8];
    const float* att_r2 = (const float*)d_in[9];
    const float* b2     = (const float*)d_in[10];
    const float* fc1W   = (const float*)d_in[11];
    const float* fc1b   = (const float*)d_in[12];
    const float* fc2W   = (const float*)d_in[13];
    const float* fc2b   = (const float*)d_in[14];
    float* out = (float*)d_out;

    char* ws = (char*)d_ws;
    size_t off = 0;
    auto alloc = [&](size_t bytes) {
        void* p = ws + off;
        off += (bytes + 255) & ~(size_t)255;
        return p;
    };
    ushort_t* Hb1    = (ushort_t*)alloc((size_t)N_NODES * CH * 2);   // GEMM1 out; reused as agg2 out
    ushort_t* Zb2    = (ushort_t*)alloc((size_t)N_NODES * CH * 2);   // agg1 out = GEMM2 in
    ushort_t* Hb2    = (ushort_t*)alloc((size_t)N_NODES * CH * 2);   // GEMM2 out
    ushort_t* W1t    = (ushort_t*)alloc((size_t)CH * KP1 * 2);
    ushort_t* W2t    = (ushort_t*)alloc((size_t)CH * CH * 2);
    float*    a_src  = (float*)alloc((size_t)N_NODES * 4);
    float*    a_dst  = (float*)alloc((size_t)N_NODES * 4);
    int*      deg    = (int*)alloc((size_t)N_NODES * 4);   // cursor directly after
    int*      cursor = (int*)alloc(256);
    int*      startA = (int*)alloc((size_t)N_NODES * 4);
    int*      fillpos= (int*)alloc((size_t)N_NODES * 4);
    int*      csr_src= (int*)alloc((size_t)N_TOT * 4);

    size_t deg_pad = ((size_t)N_NODES * 4 + 255) & ~(size_t)255;

    dim3 blk(256);
    int gemm_grid = (N_NODES + 63) / 64;        // 782 blocks, 256 thr each
    int edge_grid = (N_TOT + 255) / 256;
    int node_grid = (N_NODES + 255) / 256;
    int agg_grid  = (N_NODES + 3) / 4;
    int wtdeg_grid = WT_BLKS + edge_grid;

    // ---------------- weight conversion + CSR build ----------------
    hipMemsetAsync(deg, 0, deg_pad + 4, stream);          // deg + cursor
    convert_wt_deg<<<wtdeg_grid, blk, 0, stream>>>(W1, W1t, W2, W2t, ei, deg);
    reserve_k<<<node_grid, blk, 0, stream>>>(deg, startA, fillpos, cursor, N_NODES);
    csr_fill<<<edge_grid, blk, 0, stream>>>(ei, fillpos, csr_src);

    // ---------------- Layer 1 (x conversion fused into GEMM) ----------------
    gemm_bf16_fused_t<1><<<gemm_grid, blk, 0, stream>>>(x, W1t, Hb1, att_l1, att_r1,
                                                        a_src, a_dst, N_NODES, KP1);
    gat_aggregate<<<agg_grid, blk, 0, stream>>>(startA, deg, csr_src, a_src, a_dst,
                                                Hb1, b1, Zb2, N_NODES);

    // ---------------- Layer 2 ----------------
    gemm_bf16_fused_t<0><<<gemm_grid, blk, 0, stream>>>(Zb2, W2t, Hb2, att_l2, att_r2,
                                                        a_src, a_dst, N_NODES, CH);
    gat_aggregate<<<agg_grid, blk, 0, stream>>>(startA, deg, csr_src, a_src, a_dst,
                                                Hb2, b2, Hb1, N_NODES);

    // ---------------- Pool + head (fused, 1024 thr/graph) ----------------
    pool_head_kernel<<<N_GRAPHS, dim3(1024), 0, stream>>>(Hb1, batch, fc1W, fc1b,
                                                          fc2W, fc2b, out);
}

// Round 13
// 292.492 us; speedup vs baseline: 1.1385x; 1.0720x over previous
//
#include <hip/hip_runtime.h>
#include <hip/hip_bf16.h>

#define N_NODES 50000
#define N_EDGES 800000
#define N_TOT   (N_EDGES + N_NODES)
#define N_GRAPHS 256
#define F_IN 310
#define KP1 320          // F_IN padded to multiple of 32
#define CH 256
#define HID 128

typedef __attribute__((ext_vector_type(8))) short short8;
typedef __attribute__((ext_vector_type(4))) float f32x4;
typedef unsigned short ushort_t;

__device__ __forceinline__ float selu_f(float x) {
    const float scale = 1.0507009873554805f;
    const float alpha = 1.6732632423543772f;
    return x > 0.f ? scale * x : scale * alpha * (expm1f(x));
}

__device__ __forceinline__ ushort_t f32_to_bf16_rne(float f) {
    unsigned u = __float_as_uint(f);
    unsigned rounding = 0x7FFFu + ((u >> 16) & 1u);
    return (ushort_t)((u + rounding) >> 16);
}
__device__ __forceinline__ float bf16_to_f32(ushort_t v) {
    return __uint_as_float(((unsigned)v) << 16);
}

// ---- W conversions + deg_count fused into one launch -----------------------
#define WT_BLKS ((CH * KP1 + CH * CH + 255) / 256)
__global__ __launch_bounds__(256) void convert_wt_deg(
        const float* __restrict__ W1, ushort_t* __restrict__ W1t,
        const float* __restrict__ W2, ushort_t* __restrict__ W2t,
        const int* __restrict__ ei, int* __restrict__ deg) {
    int b = blockIdx.x;
    if (b < WT_BLKS) {
        int i = b * 256 + threadIdx.x;
        const int n1 = CH * KP1;
        if (i < n1) {
            int n = i / KP1, k = i % KP1;
            W1t[i] = (k < F_IN) ? f32_to_bf16_rne(W1[(long)k * CH + n]) : 0;
        } else {
            int j = i - n1;
            if (j >= CH * CH) return;
            int n = j / CH, k = j % CH;
            W2t[j] = f32_to_bf16_rne(W2[(long)k * CH + n]);
        }
    } else {
        int eid = (b - WT_BLKS) * 256 + threadIdx.x;
        if (eid >= N_TOT) return;
        int d = (eid < N_EDGES) ? ei[N_EDGES + eid] : eid - N_EDGES;
        atomicAdd(&deg[d], 1);
    }
}

// ------- MFMA GEMM 64x256 tile (4 waves of 64x64), 2-phase, 40KB LDS --------
// Blocks [0, gemmBlocks): GEMM. Blocks >= gemmBlocks: csr_fill edge blocks
// (latency-bound memory-side atomics overlap the compute-bound GEMM waves).
// AF32=1: A f32 reg-staged (fused x->bf16); AF32=0: A bf16 glds.
// Chunk swizzle c^(r&3) pre-applied on the GLOBAL source, same XOR on read.
template<int AF32>
__global__ __launch_bounds__(256, 4) void gemm_bf16_fused_t(
        const void* __restrict__ Asrc, const ushort_t* __restrict__ Bt,
        ushort_t* __restrict__ Cb, const float* __restrict__ att_l,
        const float* __restrict__ att_r, float* __restrict__ a_srcv,
        float* __restrict__ a_dstv, int M, int Kp, int gemmBlocks,
        const int* __restrict__ ei, int* __restrict__ fillpos,
        ushort_t* __restrict__ csr_src) {
    __shared__ __align__(16) ushort_t As[2][64 * 32];   //  8 KB
    __shared__ __align__(16) ushort_t Bs[2][256 * 32];  // 32 KB -> 40 KB total
    int tid = threadIdx.x;

    if ((int)blockIdx.x >= gemmBlocks) {                // ---- csr_fill path
        int eid = ((int)blockIdx.x - gemmBlocks) * 256 + tid;
        if (eid < N_TOT) {
            int s, d;
            if (eid < N_EDGES) { s = ei[eid]; d = ei[N_EDGES + eid]; }
            else { s = eid - N_EDGES; d = s; }
            int p = atomicAdd(&fillpos[d], 1);
            csr_src[p] = (ushort_t)s;
        }
        return;
    }

    int row0 = blockIdx.x * 64;
    int w = tid >> 6, l = tid & 63;       // wave w = output col-block
    int lr = l & 15, lc = l >> 4;
    f32x4 acc[4][4] = {};

    int srow = l >> 2;                    // 0..15
    int sc = l & 3;
    int sx = sc ^ (srow & 3);             // pre-swizzled chunk
    int garow = row0 + w * 16 + srow; if (garow >= M) garow = M - 1;
    const ushort_t* gB[4];
#pragma unroll
    for (int g = 0; g < 4; ++g)
        gB[g] = Bt + (size_t)(w * 64 + g * 16 + srow) * Kp + sx * 8;
    int nt = Kp >> 5;

    const ushort_t* gA = nullptr;
    const float* xrow = nullptr;
    if (AF32) xrow = (const float*)Asrc + (size_t)garow * F_IN;
    else      gA = (const ushort_t*)Asrc + (size_t)garow * Kp + sx * 8;

    auto stageB = [&](int sel, int k0) {
#pragma unroll
        for (int g = 0; g < 4; ++g)
            __builtin_amdgcn_global_load_lds(
                (const __attribute__((address_space(1))) void*)(gB[g] + k0),
                (__attribute__((address_space(3))) void*)(&Bs[sel][(w * 64 + g * 16) * 32]), 16, 0, 0);
    };
    auto stageA_glds = [&](int sel, int k0) {
        __builtin_amdgcn_global_load_lds(
            (const __attribute__((address_space(1))) void*)(gA + k0),
            (__attribute__((address_space(3))) void*)(&As[sel][w * 16 * 32]), 16, 0, 0);
    };
    float va[8];
    auto loadA_f32 = [&](int k0) {
        int kc = k0 + sc * 8;
        if (kc + 8 <= F_IN) {              // x rows are 8B-aligned: float2 ok
#pragma unroll
            for (int j = 0; j < 4; ++j) {
                float2 p = *(const float2*)(xrow + kc + j * 2);
                va[j * 2] = p.x; va[j * 2 + 1] = p.y;
            }
        } else {                           // K tail (cols >= 310 -> 0)
#pragma unroll
            for (int j = 0; j < 8; ++j)
                va[j] = (kc + j < F_IN) ? xrow[kc + j] : 0.f;
        }
    };
    auto writeA = [&](int sel) {
        short8 s;
#pragma unroll
        for (int j = 0; j < 8; ++j) s[j] = (short)f32_to_bf16_rne(va[j]);
        *(short8*)(&As[sel][(w * 16 + srow) * 32 + sx * 8]) = s;
    };

    if (AF32) loadA_f32(0); else stageA_glds(0, 0);
    stageB(0, 0);
    if (AF32) writeA(0);
    __syncthreads();
    int cur = 0;
    for (int t = 0; t < nt; ++t) {
        int k1 = (t + 1) << 5;
        if (t + 1 < nt) {
            if (AF32) loadA_f32(k1); else stageA_glds(cur ^ 1, k1);
            stageB(cur ^ 1, k1);
        }
        short8 af[4], bfv[4];
#pragma unroll
        for (int mi = 0; mi < 4; ++mi) {
            int r = mi * 16 + lr;
            af[mi] = *(const short8*)(&As[cur][r * 32 + ((lc ^ (r & 3)) * 8)]);
        }
#pragma unroll
        for (int ni = 0; ni < 4; ++ni) {
            int r = w * 64 + ni * 16 + lr;
            bfv[ni] = *(const short8*)(&Bs[cur][r * 32 + ((lc ^ (r & 3)) * 8)]);
        }
#pragma unroll
        for (int mi = 0; mi < 4; ++mi)
#pragma unroll
            for (int ni = 0; ni < 4; ++ni)
                acc[mi][ni] = __builtin_amdgcn_mfma_f32_16x16x32_bf16(
                    af[mi], bfv[ni], acc[mi][ni], 0, 0, 0);
        if (AF32 && t + 1 < nt) writeA(cur ^ 1);
        __syncthreads();
        cur ^= 1;
    }

    // epilogue: reuse As (free after the loop's final barrier) as scratch
    float* s_pl = (float*)&As[0][0];
    float* s_pr = s_pl + 64;
    if (tid < 128) s_pl[tid] = 0.f;
    __syncthreads();
    float al[4], ar[4];
#pragma unroll
    for (int ni = 0; ni < 4; ++ni) {
        int col = w * 64 + ni * 16 + lr;
        al[ni] = att_l[col];
        ar[ni] = att_r[col];
    }
#pragma unroll
    for (int mi = 0; mi < 4; ++mi) {
        int lrow = mi * 16 + lc * 4;
#pragma unroll
        for (int q = 0; q < 4; ++q) {
            int grow = row0 + lrow + q;
            float pl = 0.f, pr = 0.f;
#pragma unroll
            for (int ni = 0; ni < 4; ++ni) {
                float v = acc[mi][ni][q];
                pl += v * al[ni];
                pr += v * ar[ni];
                if (grow < M)
                    Cb[(size_t)grow * CH + w * 64 + ni * 16 + lr] = f32_to_bf16_rne(v);
            }
#pragma unroll
            for (int off = 1; off < 16; off <<= 1) {
                pl += __shfl_xor(pl, off);
                pr += __shfl_xor(pr, off);
            }
            if (lr == 0) {
                atomicAdd(&s_pl[lrow + q], pl);
                atomicAdd(&s_pr[lrow + q], pr);
            }
        }
    }
    __syncthreads();
    if (tid < 64 && row0 + tid < M) {
        a_srcv[row0 + tid] = s_pl[tid];
        a_dstv[row0 + tid] = s_pr[tid];
    }
}

// ---------------- CSR build: range reserve ----------------------------------
__global__ __launch_bounds__(256) void reserve_k(
        const int* __restrict__ deg, int* __restrict__ start,
        int* __restrict__ fillpos, int* __restrict__ cursor, int n) {
    int i = blockIdx.x * blockDim.x + threadIdx.x;
    if (i >= n) return;
    int s = atomicAdd(cursor, deg[i]);
    start[i] = s;
    fillpos[i] = s;
}

// ---- fused per-dst GAT aggregate: SINGLE edge pass (ushort csr) ------------
// out = (sum_e ex*h[src]) * inv (no max shift). Per 64-edge chunk:
// lane-parallel (src, ex) in registers; gather loop broadcasts via __shfl;
// 8 h-row gathers in flight.
__global__ __launch_bounds__(256) void gat_aggregate(
        const int* __restrict__ start, const int* __restrict__ deg,
        const ushort_t* __restrict__ csr_src,
        const float* __restrict__ a_src, const float* __restrict__ a_dst,
        const ushort_t* __restrict__ h, const float* __restrict__ bias,
        ushort_t* __restrict__ out_bf, int n) {
    int wid = threadIdx.x >> 6;
    int lane = threadIdx.x & 63;
    int node = blockIdx.x * 4 + wid;
    if (node >= n) return;
    int s0 = start[node];
    int dg = deg[node];
    float ad = a_dst[node];

    float sum_l = 0.f;
    float4 acc = {0.f, 0.f, 0.f, 0.f};
    for (int c = 0; c < dg; c += 64) {
        int nc = min(64, dg - c);
        int s_l = 0; float ex_l = 0.f;
        if (lane < nc) {
            s_l = csr_src[s0 + c + lane];
            float e = a_src[s_l] + ad;
            e = fmaxf(e, 0.2f * e);
            ex_l = __expf(e);
            sum_l += ex_l;
        }
        int j = 0;
        for (; j + 8 <= nc; j += 8) {
            int si[8]; float xi[8]; ushort4 hv[8];
#pragma unroll
            for (int k = 0; k < 8; ++k) {
                si[k] = __shfl(s_l, j + k);
                xi[k] = __shfl(ex_l, j + k);
            }
#pragma unroll
            for (int k = 0; k < 8; ++k)
                hv[k] = *(const ushort4*)(h + (long)si[k] * CH + lane * 4);
#pragma unroll
            for (int k = 0; k < 8; ++k) {
                acc.x += xi[k] * bf16_to_f32(hv[k].x);
                acc.y += xi[k] * bf16_to_f32(hv[k].y);
                acc.z += xi[k] * bf16_to_f32(hv[k].z);
                acc.w += xi[k] * bf16_to_f32(hv[k].w);
            }
        }
        for (; j < nc; ++j) {
            int sj = __shfl(s_l, j);
            float xj = __shfl(ex_l, j);
            ushort4 hv = *(const ushort4*)(h + (long)sj * CH + lane * 4);
            acc.x += xj * bf16_to_f32(hv.x);
            acc.y += xj * bf16_to_f32(hv.y);
            acc.z += xj * bf16_to_f32(hv.z);
            acc.w += xj * bf16_to_f32(hv.w);
        }
    }
    float sum = sum_l;
#pragma unroll
    for (int off = 32; off > 0; off >>= 1) sum += __shfl_xor(sum, off);
    float inv = 1.f / fmaxf(sum, 1e-16f);

    float4 bv = *(const float4*)(bias + lane * 4);
    ushort4 ob;
    ob.x = f32_to_bf16_rne(selu_f(acc.x * inv + bv.x));
    ob.y = f32_to_bf16_rne(selu_f(acc.y * inv + bv.y));
    ob.z = f32_to_bf16_rne(selu_f(acc.z * inv + bv.z));
    ob.w = f32_to_bf16_rne(selu_f(acc.w * inv + bv.w));
    *(ushort4*)(out_bf + (long)node * CH + lane * 4) = ob;
}

// ---- fused pool + head: one block (1024 thr) per graph ---------------------
__global__ __launch_bounds__(1024) void pool_head_kernel(
        const ushort_t* __restrict__ h, const int* __restrict__ batch,
        const float* __restrict__ fc1W, const float* __restrict__ fc1b,
        const float* __restrict__ fc2W, const float* __restrict__ fc2b,
        float* __restrict__ out) {
    __shared__ float part[4][CH];
    __shared__ float row[CH];
    __shared__ float part2[8][HID];
    __shared__ float hrow[HID];
    __shared__ float logits[2];
    int g = blockIdx.x;
    int tid = threadIdx.x;
    int t = tid & 255;
    int quad = tid >> 8;              // 0..3
    int lo, hi;
    { int a = 0, b = N_NODES;
      while (a < b) { int mid = (a + b) >> 1; if (batch[mid] < g) a = mid + 1; else b = mid; }
      lo = a; }
    { int a = lo, b = N_NODES;
      while (a < b) { int mid = (a + b) >> 1; if (batch[mid] < g + 1) a = mid + 1; else b = mid; }
      hi = a; }
    float a0 = 0.f, a1 = 0.f;
    int i = lo + quad;
    for (; i + 4 < hi; i += 8) {
        a0 += bf16_to_f32(h[(long)i * CH + t]);
        a1 += bf16_to_f32(h[(long)(i + 4) * CH + t]);
    }
    for (; i < hi; i += 4) a0 += bf16_to_f32(h[(long)i * CH + t]);
    part[quad][t] = a0 + a1;
    __syncthreads();
    if (quad == 0) {
        float cnt = (float)(hi - lo);
        float acc = (part[0][t] + part[1][t]) + (part[2][t] + part[3][t]);
        row[t] = selu_f(acc / fmaxf(cnt, 1.f));
    }
    __syncthreads();
    {   // fc1: tid -> (seg = tid>>7 in 0..7, o = tid&127)
        int o = tid & 127;
        int seg = tid >> 7;
        float s = 0.f;
        int k0 = seg * 32;
        for (int k = k0; k < k0 + 32; ++k) s += row[k] * fc1W[k * HID + o];
        part2[seg][o] = s;
    }
    __syncthreads();
    if (tid < HID) {
        float s = fc1b[tid];
#pragma unroll
        for (int j = 0; j < 8; ++j) s += part2[j][tid];
        hrow[tid] = selu_f(s);
    }
    __syncthreads();
    if (tid < 2) {
        float a = fc2b[tid];
        for (int k = 0; k < HID; k++) a += hrow[k] * fc2W[k * 2 + tid];
        logits[tid] = a;
    }
    __syncthreads();
    if (tid < 2) {
        float m = fmaxf(logits[0], logits[1]);
        float lse = logf(expf(logits[0] - m) + expf(logits[1] - m)) + m;
        out[g * 2 + tid] = logits[tid] - lse;
    }
}

extern "C" void kernel_launch(void* const* d_in, const int* in_sizes, int n_in,
                              void* d_out, int out_size, void* d_ws, size_t ws_size,
                              hipStream_t stream) {
    const float* x      = (const float*)d_in[0];
    const int*   ei     = (const int*)d_in[1];
    const int*   batch  = (const int*)d_in[2];
    const float* W1     = (const float*)d_in[3];
    const float* att_l1 = (const float*)d_in[4];
    const float* att_r1 = (const float*)d_in[5];
    const float* b1     = (const float*)d_in[6];
    const float* W2     = (const float*)d_in[7];
    const float* att_l2 = (const float*)d_in[8];
    const float* att_r2 = (const float*)d_in[9];
    const float* b2     = (const float*)d_in[10];
    const float* fc1W   = (const float*)d_in[11];
    const float* fc1b   = (const float*)d_in[12];
    const float* fc2W   = (const float*)d_in[13];
    const float* fc2b   = (const float*)d_in[14];
    float* out = (float*)d_out;

    char* ws = (char*)d_ws;
    size_t off = 0;
    auto alloc = [&](size_t bytes) {
        void* p = ws + off;
        off += (bytes + 255) & ~(size_t)255;
        return p;
    };
    ushort_t* Hb1    = (ushort_t*)alloc((size_t)N_NODES * CH * 2);   // GEMM1 out; reused as agg2 out
    ushort_t* Zb2    = (ushort_t*)alloc((size_t)N_NODES * CH * 2);   // agg1 out = GEMM2 in
    ushort_t* Hb2    = (ushort_t*)alloc((size_t)N_NODES * CH * 2);   // GEMM2 out
    ushort_t* W1t    = (ushort_t*)alloc((size_t)CH * KP1 * 2);
    ushort_t* W2t    = (ushort_t*)alloc((size_t)CH * CH * 2);
    float*    a_src  = (float*)alloc((size_t)N_NODES * 4);
    float*    a_dst  = (float*)alloc((size_t)N_NODES * 4);
    int*      deg    = (int*)alloc((size_t)N_NODES * 4);   // cursor directly after
    int*      cursor = (int*)alloc(256);
    int*      startA = (int*)alloc((size_t)N_NODES * 4);
    int*      fillpos= (int*)alloc((size_t)N_NODES * 4);
    ushort_t* csr_src= (ushort_t*)alloc((size_t)N_TOT * 2);

    size_t deg_pad = ((size_t)N_NODES * 4 + 255) & ~(size_t)255;

    dim3 blk(256);
    int gemm_grid = (N_NODES + 63) / 64;        // 782 blocks, 256 thr each
    int edge_grid = (N_TOT + 255) / 256;        // 3321 fill blocks
    int node_grid = (N_NODES + 255) / 256;
    int agg_grid  = (N_NODES + 3) / 4;
    int wtdeg_grid = WT_BLKS + edge_grid;

    // ---------------- weight conversion + deg count ----------------
    hipMemsetAsync(deg, 0, deg_pad + 4, stream);          // deg + cursor
    convert_wt_deg<<<wtdeg_grid, blk, 0, stream>>>(W1, W1t, W2, W2t, ei, deg);
    reserve_k<<<node_grid, blk, 0, stream>>>(deg, startA, fillpos, cursor, N_NODES);

    // ---------------- Layer 1 (x->bf16 fused; csr_fill overlapped) ----------
    gemm_bf16_fused_t<1><<<gemm_grid + edge_grid, blk, 0, stream>>>(
        x, W1t, Hb1, att_l1, att_r1, a_src, a_dst, N_NODES, KP1,
        gemm_grid, ei, fillpos, csr_src);
    gat_aggregate<<<agg_grid, blk, 0, stream>>>(startA, deg, csr_src, a_src, a_dst,
                                                Hb1, b1, Zb2, N_NODES);

    // ---------------- Layer 2 ----------------
    gemm_bf16_fused_t<0><<<gemm_grid, blk, 0, stream>>>(
        Zb2, W2t, Hb2, att_l2, att_r2, a_src, a_dst, N_NODES, CH,
        gemm_grid, (const int*)nullptr, (int*)nullptr, (ushort_t*)nullptr);
    gat_aggregate<<<agg_grid, blk, 0, stream>>>(startA, deg, csr_src, a_src, a_dst,
                                                Hb2, b2, Hb1, N_NODES);

    // ---------------- Pool + head (fused, 1024 thr/graph) ----------------
    pool_head_kernel<<<N_GRAPHS, dim3(1024), 0, stream>>>(Hb1, batch, fc1W, fc1b,
                                                          fc2W, fc2b, out);
}

// Round 14
// 288.985 us; speedup vs baseline: 1.1524x; 1.0121x over previous
//
#include <hip/hip_runtime.h>
#include <hip/hip_bf16.h>

#define N_NODES 50000
#define N_EDGES 800000
#define N_TOT   (N_EDGES + N_NODES)
#define N_GRAPHS 256
#define F_IN 310
#define KP1 320          // F_IN padded to multiple of 32
#define CH 256
#define HID 128

typedef __attribute__((ext_vector_type(8))) short short8;
typedef __attribute__((ext_vector_type(4))) float f32x4;
typedef unsigned short ushort_t;

__device__ __forceinline__ float selu_f(float x) {
    const float scale = 1.0507009873554805f;
    const float alpha = 1.6732632423543772f;
    return x > 0.f ? scale * x : scale * alpha * (expm1f(x));
}

__device__ __forceinline__ ushort_t f32_to_bf16_rne(float f) {
    unsigned u = __float_as_uint(f);
    unsigned rounding = 0x7FFFu + ((u >> 16) & 1u);
    return (ushort_t)((u + rounding) >> 16);
}
__device__ __forceinline__ float bf16_to_f32(ushort_t v) {
    return __uint_as_float(((unsigned)v) << 16);
}

// ---- W conversions + deg_count fused into one launch -----------------------
#define WT_BLKS ((CH * KP1 + CH * CH + 255) / 256)
__global__ __launch_bounds__(256) void convert_wt_deg(
        const float* __restrict__ W1, ushort_t* __restrict__ W1t,
        const float* __restrict__ W2, ushort_t* __restrict__ W2t,
        const int* __restrict__ ei, int* __restrict__ deg) {
    int b = blockIdx.x;
    if (b < WT_BLKS) {
        int i = b * 256 + threadIdx.x;
        const int n1 = CH * KP1;
        if (i < n1) {
            int n = i / KP1, k = i % KP1;
            W1t[i] = (k < F_IN) ? f32_to_bf16_rne(W1[(long)k * CH + n]) : 0;
        } else {
            int j = i - n1;
            if (j >= CH * CH) return;
            int n = j / CH, k = j % CH;
            W2t[j] = f32_to_bf16_rne(W2[(long)k * CH + n]);
        }
    } else {
        int eid = (b - WT_BLKS) * 256 + threadIdx.x;
        if (eid >= N_TOT) return;
        int d = (eid < N_EDGES) ? ei[N_EDGES + eid] : eid - N_EDGES;
        atomicAdd(&deg[d], 1);
    }
}

// ------- MFMA GEMM 64x256 tile (4 waves of 64x64), 2-phase, 40KB LDS --------
// FILL=1 (layer 1 only): blocks >= gemmBlocks run csr_fill (latency-bound
// atomics overlapping the GEMM). FILL=0: fill code compiled OUT (clean
// codegen for layer 2 -- round-13 showed the co-compiled branch cost ~20us).
// LDS swizzle: chunk' = c ^ (r&3) ^ ((r>>2)&3)  -> 2-way (free) instead of
// 4-way bank conflicts; XOR involution applied on the GLOBAL source for glds
// (linear dest) and on the ds_write address for the f32-A path (rule #21).
template<int AF32, int FILL>
__global__ __launch_bounds__(256, 4) void gemm_k(
        const void* __restrict__ Asrc, const ushort_t* __restrict__ Bt,
        ushort_t* __restrict__ Cb, const float* __restrict__ att_l,
        const float* __restrict__ att_r, float* __restrict__ a_srcv,
        float* __restrict__ a_dstv, int M, int Kp, int gemmBlocks,
        const int* __restrict__ ei, int* __restrict__ fillpos,
        const int* __restrict__ startA, ushort_t* __restrict__ csr_src) {
    __shared__ __align__(16) ushort_t As[2][64 * 32];   //  8 KB
    __shared__ __align__(16) ushort_t Bs[2][256 * 32];  // 32 KB -> 40 KB total
    int tid = threadIdx.x;

    if constexpr (FILL) {
        if ((int)blockIdx.x >= gemmBlocks) {            // ---- csr_fill path
            int eid = ((int)blockIdx.x - gemmBlocks) * 256 + tid;
            if (eid < N_TOT) {
                if (eid < N_EDGES) {
                    int s = ei[eid], d = ei[N_EDGES + eid];
                    int p = atomicAdd(&fillpos[d], 1);
                    csr_src[p] = (ushort_t)s;
                } else {
                    int d = eid - N_EDGES;              // self-loop: fixed slot
                    csr_src[startA[d]] = (ushort_t)d;   // no atomic
                }
            }
            return;
        }
    }

    int row0 = blockIdx.x * 64;
    int w = tid >> 6, l = tid & 63;       // wave w = output col-block
    int lr = l & 15, lc = l >> 4;
    f32x4 acc[4][4] = {};

    int srow = l >> 2;                    // 0..15
    int sc = l & 3;
    int sx = sc ^ (srow & 3) ^ ((srow >> 2) & 3);       // pre-swizzled chunk
    int garow = row0 + w * 16 + srow; if (garow >= M) garow = M - 1;
    const ushort_t* gB[4];
#pragma unroll
    for (int g = 0; g < 4; ++g)
        gB[g] = Bt + (size_t)(w * 64 + g * 16 + srow) * Kp + sx * 8;
    int nt = Kp >> 5;

    const ushort_t* gA = nullptr;
    const float* xrow = nullptr;
    if (AF32) xrow = (const float*)Asrc + (size_t)garow * F_IN;
    else      gA = (const ushort_t*)Asrc + (size_t)garow * Kp + sx * 8;

    auto stageB = [&](int sel, int k0) {
#pragma unroll
        for (int g = 0; g < 4; ++g)
            __builtin_amdgcn_global_load_lds(
                (const __attribute__((address_space(1))) void*)(gB[g] + k0),
                (__attribute__((address_space(3))) void*)(&Bs[sel][(w * 64 + g * 16) * 32]), 16, 0, 0);
    };
    auto stageA_glds = [&](int sel, int k0) {
        __builtin_amdgcn_global_load_lds(
            (const __attribute__((address_space(1))) void*)(gA + k0),
            (__attribute__((address_space(3))) void*)(&As[sel][w * 16 * 32]), 16, 0, 0);
    };
    float va[8];
    auto loadA_f32 = [&](int k0) {
        int kc = k0 + sc * 8;             // natural chunk (write addr swizzled)
        if (kc + 8 <= F_IN) {             // x rows are 8B-aligned: float2 ok
#pragma unroll
            for (int j = 0; j < 4; ++j) {
                float2 p = *(const float2*)(xrow + kc + j * 2);
                va[j * 2] = p.x; va[j * 2 + 1] = p.y;
            }
        } else {                          // K tail (cols >= 310 -> 0)
#pragma unroll
            for (int j = 0; j < 8; ++j)
                va[j] = (kc + j < F_IN) ? xrow[kc + j] : 0.f;
        }
    };
    auto writeA = [&](int sel) {
        short8 s;
#pragma unroll
        for (int j = 0; j < 8; ++j) s[j] = (short)f32_to_bf16_rne(va[j]);
        *(short8*)(&As[sel][(w * 16 + srow) * 32 + sx * 8]) = s;
    };

    if (AF32) loadA_f32(0); else stageA_glds(0, 0);
    stageB(0, 0);
    if (AF32) writeA(0);
    __syncthreads();
    int cur = 0;
    for (int t = 0; t < nt; ++t) {
        int k1 = (t + 1) << 5;
        if (t + 1 < nt) {
            if (AF32) loadA_f32(k1); else stageA_glds(cur ^ 1, k1);
            stageB(cur ^ 1, k1);
        }
        short8 af[4], bfv[4];
#pragma unroll
        for (int mi = 0; mi < 4; ++mi) {
            int r = mi * 16 + lr;
            af[mi] = *(const short8*)(&As[cur][r * 32 + ((lc ^ (r & 3) ^ ((r >> 2) & 3)) * 8)]);
        }
#pragma unroll
        for (int ni = 0; ni < 4; ++ni) {
            int r = w * 64 + ni * 16 + lr;
            bfv[ni] = *(const short8*)(&Bs[cur][r * 32 + ((lc ^ (r & 3) ^ ((r >> 2) & 3)) * 8)]);
        }
#pragma unroll
        for (int mi = 0; mi < 4; ++mi)
#pragma unroll
            for (int ni = 0; ni < 4; ++ni)
                acc[mi][ni] = __builtin_amdgcn_mfma_f32_16x16x32_bf16(
                    af[mi], bfv[ni], acc[mi][ni], 0, 0, 0);
        if (AF32 && t + 1 < nt) writeA(cur ^ 1);
        __syncthreads();
        cur ^= 1;
    }

    // epilogue: reuse As (free after the loop's final barrier) as scratch
    float* s_pl = (float*)&As[0][0];
    float* s_pr = s_pl + 64;
    if (tid < 128) s_pl[tid] = 0.f;
    __syncthreads();
    float al[4], ar[4];
#pragma unroll
    for (int ni = 0; ni < 4; ++ni) {
        int col = w * 64 + ni * 16 + lr;
        al[ni] = att_l[col];
        ar[ni] = att_r[col];
    }
#pragma unroll
    for (int mi = 0; mi < 4; ++mi) {
        int lrow = mi * 16 + lc * 4;
#pragma unroll
        for (int q = 0; q < 4; ++q) {
            int grow = row0 + lrow + q;
            float pl = 0.f, pr = 0.f;
#pragma unroll
            for (int ni = 0; ni < 4; ++ni) {
                float v = acc[mi][ni][q];
                pl += v * al[ni];
                pr += v * ar[ni];
                if (grow < M)
                    Cb[(size_t)grow * CH + w * 64 + ni * 16 + lr] = f32_to_bf16_rne(v);
            }
#pragma unroll
            for (int off = 1; off < 16; off <<= 1) {
                pl += __shfl_xor(pl, off);
                pr += __shfl_xor(pr, off);
            }
            if (lr == 0) {
                atomicAdd(&s_pl[lrow + q], pl);
                atomicAdd(&s_pr[lrow + q], pr);
            }
        }
    }
    __syncthreads();
    if (tid < 64 && row0 + tid < M) {
        a_srcv[row0 + tid] = s_pl[tid];
        a_dstv[row0 + tid] = s_pr[tid];
    }
}

// ---------------- CSR build: range reserve (slot 0 = self-loop) -------------
__global__ __launch_bounds__(256) void reserve_k(
        const int* __restrict__ deg, int* __restrict__ start,
        int* __restrict__ fillpos, int* __restrict__ cursor, int n) {
    int i = blockIdx.x * blockDim.x + threadIdx.x;
    if (i >= n) return;
    int s = atomicAdd(cursor, deg[i]);
    start[i] = s;
    fillpos[i] = s + 1;          // slot s reserved for the self-loop
}

// ---- fused per-dst GAT aggregate: SINGLE edge pass (ushort csr) ------------
// out = (sum_e ex*h[src]) * inv (no max shift). Per 64-edge chunk:
// lane-parallel (src, ex) in registers; gather loop broadcasts via __shfl;
// 8 h-row gathers in flight.
__global__ __launch_bounds__(256) void gat_aggregate(
        const int* __restrict__ start, const int* __restrict__ deg,
        const ushort_t* __restrict__ csr_src,
        const float* __restrict__ a_src, const float* __restrict__ a_dst,
        const ushort_t* __restrict__ h, const float* __restrict__ bias,
        ushort_t* __restrict__ out_bf, int n) {
    int wid = threadIdx.x >> 6;
    int lane = threadIdx.x & 63;
    int node = blockIdx.x * 4 + wid;
    if (node >= n) return;
    int s0 = start[node];
    int dg = deg[node];
    float ad = a_dst[node];

    float sum_l = 0.f;
    float4 acc = {0.f, 0.f, 0.f, 0.f};
    for (int c = 0; c < dg; c += 64) {
        int nc = min(64, dg - c);
        int s_l = 0; float ex_l = 0.f;
        if (lane < nc) {
            s_l = csr_src[s0 + c + lane];
            float e = a_src[s_l] + ad;
            e = fmaxf(e, 0.2f * e);
            ex_l = __expf(e);
            sum_l += ex_l;
        }
        int j = 0;
        for (; j + 8 <= nc; j += 8) {
            int si[8]; float xi[8]; ushort4 hv[8];
#pragma unroll
            for (int k = 0; k < 8; ++k) {
                si[k] = __shfl(s_l, j + k);
                xi[k] = __shfl(ex_l, j + k);
            }
#pragma unroll
            for (int k = 0; k < 8; ++k)
                hv[k] = *(const ushort4*)(h + (long)si[k] * CH + lane * 4);
#pragma unroll
            for (int k = 0; k < 8; ++k) {
                acc.x += xi[k] * bf16_to_f32(hv[k].x);
                acc.y += xi[k] * bf16_to_f32(hv[k].y);
                acc.z += xi[k] * bf16_to_f32(hv[k].z);
                acc.w += xi[k] * bf16_to_f32(hv[k].w);
            }
        }
        for (; j < nc; ++j) {
            int sj = __shfl(s_l, j);
            float xj = __shfl(ex_l, j);
            ushort4 hv = *(const ushort4*)(h + (long)sj * CH + lane * 4);
            acc.x += xj * bf16_to_f32(hv.x);
            acc.y += xj * bf16_to_f32(hv.y);
            acc.z += xj * bf16_to_f32(hv.z);
            acc.w += xj * bf16_to_f32(hv.w);
        }
    }
    float sum = sum_l;
#pragma unroll
    for (int off = 32; off > 0; off >>= 1) sum += __shfl_xor(sum, off);
    float inv = 1.f / fmaxf(sum, 1e-16f);

    float4 bv = *(const float4*)(bias + lane * 4);
    ushort4 ob;
    ob.x = f32_to_bf16_rne(selu_f(acc.x * inv + bv.x));
    ob.y = f32_to_bf16_rne(selu_f(acc.y * inv + bv.y));
    ob.z = f32_to_bf16_rne(selu_f(acc.z * inv + bv.z));
    ob.w = f32_to_bf16_rne(selu_f(acc.w * inv + bv.w));
    *(ushort4*)(out_bf + (long)node * CH + lane * 4) = ob;
}

// ---- fused pool + head: one block (1024 thr) per graph ---------------------
__global__ __launch_bounds__(1024) void pool_head_kernel(
        const ushort_t* __restrict__ h, const int* __restrict__ batch,
        const float* __restrict__ fc1W, const float* __restrict__ fc1b,
        const float* __restrict__ fc2W, const float* __restrict__ fc2b,
        float* __restrict__ out) {
    __shared__ float part[4][CH];
    __shared__ float row[CH];
    __shared__ float part2[8][HID];
    __shared__ float hrow[HID];
    __shared__ float logits[2];
    int g = blockIdx.x;
    int tid = threadIdx.x;
    int t = tid & 255;
    int quad = tid >> 8;              // 0..3
    int lo, hi;
    { int a = 0, b = N_NODES;
      while (a < b) { int mid = (a + b) >> 1; if (batch[mid] < g) a = mid + 1; else b = mid; }
      lo = a; }
    { int a = lo, b = N_NODES;
      while (a < b) { int mid = (a + b) >> 1; if (batch[mid] < g + 1) a = mid + 1; else b = mid; }
      hi = a; }
    float a0 = 0.f, a1 = 0.f;
    int i = lo + quad;
    for (; i + 4 < hi; i += 8) {
        a0 += bf16_to_f32(h[(long)i * CH + t]);
        a1 += bf16_to_f32(h[(long)(i + 4) * CH + t]);
    }
    for (; i < hi; i += 4) a0 += bf16_to_f32(h[(long)i * CH + t]);
    part[quad][t] = a0 + a1;
    __syncthreads();
    if (quad == 0) {
        float cnt = (float)(hi - lo);
        float acc = (part[0][t] + part[1][t]) + (part[2][t] + part[3][t]);
        row[t] = selu_f(acc / fmaxf(cnt, 1.f));
    }
    __syncthreads();
    {   // fc1: tid -> (seg = tid>>7 in 0..7, o = tid&127)
        int o = tid & 127;
        int seg = tid >> 7;
        float s = 0.f;
        int k0 = seg * 32;
        for (int k = k0; k < k0 + 32; ++k) s += row[k] * fc1W[k * HID + o];
        part2[seg][o] = s;
    }
    __syncthreads();
    if (tid < HID) {
        float s = fc1b[tid];
#pragma unroll
        for (int j = 0; j < 8; ++j) s += part2[j][tid];
        hrow[tid] = selu_f(s);
    }
    __syncthreads();
    if (tid < 2) {
        float a = fc2b[tid];
        for (int k = 0; k < HID; k++) a += hrow[k] * fc2W[k * 2 + tid];
        logits[tid] = a;
    }
    __syncthreads();
    if (tid < 2) {
        float m = fmaxf(logits[0], logits[1]);
        float lse = logf(expf(logits[0] - m) + expf(logits[1] - m)) + m;
        out[g * 2 + tid] = logits[tid] - lse;
    }
}

extern "C" void kernel_launch(void* const* d_in, const int* in_sizes, int n_in,
                              void* d_out, int out_size, void* d_ws, size_t ws_size,
                              hipStream_t stream) {
    const float* x      = (const float*)d_in[0];
    const int*   ei     = (const int*)d_in[1];
    const int*   batch  = (const int*)d_in[2];
    const float* W1     = (const float*)d_in[3];
    const float* att_l1 = (const float*)d_in[4];
    const float* att_r1 = (const float*)d_in[5];
    const float* b1     = (const float*)d_in[6];
    const float* W2     = (const float*)d_in[7];
    const float* att_l2 = (const float*)d_in[8];
    const float* att_r2 = (const float*)d_in[9];
    const float* b2     = (const float*)d_in[10];
    const float* fc1W   = (const float*)d_in[11];
    const float* fc1b   = (const float*)d_in[12];
    const float* fc2W   = (const float*)d_in[13];
    const float* fc2b   = (const float*)d_in[14];
    float* out = (float*)d_out;

    char* ws = (char*)d_ws;
    size_t off = 0;
    auto alloc = [&](size_t bytes) {
        void* p = ws + off;
        off += (bytes + 255) & ~(size_t)255;
        return p;
    };
    ushort_t* Hb1    = (ushort_t*)alloc((size_t)N_NODES * CH * 2);   // GEMM1 out; reused as agg2 out
    ushort_t* Zb2    = (ushort_t*)alloc((size_t)N_NODES * CH * 2);   // agg1 out = GEMM2 in
    ushort_t* Hb2    = (ushort_t*)alloc((size_t)N_NODES * CH * 2);   // GEMM2 out
    ushort_t* W1t    = (ushort_t*)alloc((size_t)CH * KP1 * 2);
    ushort_t* W2t    = (ushort_t*)alloc((size_t)CH * CH * 2);
    float*    a_src  = (float*)alloc((size_t)N_NODES * 4);
    float*    a_dst  = (float*)alloc((size_t)N_NODES * 4);
    int*      deg    = (int*)alloc((size_t)N_NODES * 4);   // cursor directly after
    int*      cursor = (int*)alloc(256);
    int*      startA = (int*)alloc((size_t)N_NODES * 4);
    int*      fillpos= (int*)alloc((size_t)N_NODES * 4);
    ushort_t* csr_src= (ushort_t*)alloc((size_t)N_TOT * 2);

    size_t deg_pad = ((size_t)N_NODES * 4 + 255) & ~(size_t)255;

    dim3 blk(256);
    int gemm_grid = (N_NODES + 63) / 64;        // 782 blocks, 256 thr each
    int edge_grid = (N_TOT + 255) / 256;        // 3321 fill blocks
    int node_grid = (N_NODES + 255) / 256;
    int agg_grid  = (N_NODES + 3) / 4;
    int wtdeg_grid = WT_BLKS + edge_grid;

    // ---------------- weight conversion + deg count ----------------
    hipMemsetAsync(deg, 0, deg_pad + 4, stream);          // deg + cursor
    convert_wt_deg<<<wtdeg_grid, blk, 0, stream>>>(W1, W1t, W2, W2t, ei, deg);
    reserve_k<<<node_grid, blk, 0, stream>>>(deg, startA, fillpos, cursor, N_NODES);

    // ---------------- Layer 1 (x->bf16 fused; csr_fill overlapped) ----------
    gemm_k<1, 1><<<gemm_grid + edge_grid, blk, 0, stream>>>(
        x, W1t, Hb1, att_l1, att_r1, a_src, a_dst, N_NODES, KP1,
        gemm_grid, ei, fillpos, startA, csr_src);
    gat_aggregate<<<agg_grid, blk, 0, stream>>>(startA, deg, csr_src, a_src, a_dst,
                                                Hb1, b1, Zb2, N_NODES);

    // ---------------- Layer 2 (no fill code compiled in) ----------------
    gemm_k<0, 0><<<gemm_grid, blk, 0, stream>>>(
        Zb2, W2t, Hb2, att_l2, att_r2, a_src, a_dst, N_NODES, CH,
        gemm_grid, (const int*)nullptr, (int*)nullptr,
        (const int*)nullptr, (ushort_t*)nullptr);
    gat_aggregate<<<agg_grid, blk, 0, stream>>>(startA, deg, csr_src, a_src, a_dst,
                                                Hb2, b2, Hb1, N_NODES);

    // ---------------- Pool + head (fused, 1024 thr/graph) ----------------
    pool_head_kernel<<<N_GRAPHS, dim3(1024), 0, stream>>>(Hb1, batch, fc1W, fc1b,
                                                          fc2W, fc2b, out);
}